// Round 15
// baseline (164.833 us; speedup 1.0000x reference)
//
#include <hip/hip_runtime.h>
#include <hip/hip_bf16.h>
#include <math.h>

#define DEV_INLINE __device__ __forceinline__

typedef __attribute__((ext_vector_type(4))) float f32x4;
typedef __attribute__((ext_vector_type(16))) float f32x16;
typedef __attribute__((ext_vector_type(8))) short short8;
typedef __attribute__((ext_vector_type(4))) unsigned short u16x4;

// ---------- bf16 helpers ----------
DEV_INLINE unsigned short f2bf(float f) {
    unsigned int u = __builtin_bit_cast(unsigned int, f);
    u += 0x7FFFu + ((u >> 16) & 1u);   // round-to-nearest-even
    return (unsigned short)(u >> 16);
}
DEV_INLINE unsigned cvt_pk_bf16(float lo, float hi) {
    unsigned r;
    asm("v_cvt_pk_bf16_f32 %0, %1, %2" : "=v"(r) : "v"(lo), "v"(hi));
    return r;
}

// ---------- async global->LDS (16B per lane) ----------
DEV_INLINE void gload16(const void* g, void* l) {
    __builtin_amdgcn_global_load_lds(
        (const __attribute__((address_space(1))) unsigned int*)g,
        (__attribute__((address_space(3))) unsigned int*)l, 16, 0, 0);
}

// ---------- constants ----------
#define BB 2
#define TT 2048
#define DD 1024
#define HH 16
#define HDIM 64
#define BT (BB*TT)        // 4096
#define N3 (3*DD)         // 3072
#define NROWS (BB*HH*TT)  // 65536 attention rows
#define K1ATT 0.18033688011112042f   // (1/8) * log2(e), folded into Q

#define SPLIT 2
#define KVLEN (TT/SPLIT)   // 1024 keys per split
#define NTILE (KVLEN/64)   // 16 tiles (64 keys) per split

// ============================================================
// Fused prep kernel (block-range dispatch)
// ============================================================
DEV_INLINE void do_transpose(const float* __restrict__ in, unsigned short* __restrict__ out,
                             int K, int N, int bx, float (*tile)[66], int tid) {
    int nb = N >> 6;
    int n0 = (bx % nb) * 64, k0 = (bx / nb) * 64;
    int tx = tid & 63, ty = tid >> 6;
#pragma unroll
    for (int r = ty; r < 64; r += 4)
        tile[r][tx] = in[(size_t)(k0 + r) * N + n0 + tx];
    __syncthreads();
#pragma unroll
    for (int r = ty; r < 64; r += 4)
        out[(size_t)(n0 + r) * K + k0 + tx] = f2bf(tile[tx][r]);
}

__global__ __launch_bounds__(256)
void k_prep(const float* __restrict__ x, const float* __restrict__ W_qkv,
            const float* __restrict__ W_out, const unsigned char* __restrict__ mask,
            unsigned short* __restrict__ xb, float2* __restrict__ cs,
            unsigned short* __restrict__ wqkvt, unsigned short* __restrict__ woutt,
            unsigned* __restrict__ mbits) {
    __shared__ float tile[64][66];
    const int bid = blockIdx.x, tid = threadIdx.x;
    if (bid < 4096) {
        int i = bid * 256 + tid;
        f32x4 v = ((const f32x4*)x)[i];
        u16x4 o;
        o[0] = f2bf(v[0]); o[1] = f2bf(v[1]); o[2] = f2bf(v[2]); o[3] = f2bf(v[3]);
        ((u16x4*)xb)[i] = o;
    } else if (bid < 4352) {
        int i = (bid - 4096) * 256 + tid;
        int t = i >> 5, f = i & 31;
        float inv = powf(10000.0f, -(float)f / 32.0f);
        float ang = (float)t * inv;
        cs[i] = make_float2(cosf(ang), sinf(ang));
    } else if (bid < 5120) {
        do_transpose(W_qkv, wqkvt, DD, N3, bid - 4352, tile, tid);
    } else if (bid < 5376) {
        do_transpose(W_out, woutt, DD, DD, bid - 5120, tile, tid);
    } else {
        if (tid < BB * 64) {
            int b = tid >> 6, w = tid & 63;
            unsigned v = 0;
#pragma unroll
            for (int j = 0; j < 32; ++j)
                v |= (mask[b * TT + w * 32 + j] ? 1u : 0u) << j;
            mbits[tid] = v;
        }
    }
}

// ============================================================
// QKV GEMM + fused bias + RoPE + scatter (R6-proven loop).
// 1D grid, 2D XCD chunk: 8 XCDs as 4(m)x2(n).
// ============================================================
__global__ __launch_bounds__(256)
void k_gemm_qkv(const unsigned short* __restrict__ A,
                const unsigned short* __restrict__ Bt,
                const float* __restrict__ bias,
                const float2* __restrict__ cs,
                unsigned short* __restrict__ Qb,
                unsigned short* __restrict__ Kb,
                unsigned short* __restrict__ Vrow) {
    __shared__ unsigned short As[128 * 32];
    __shared__ unsigned short Bs[128 * 32];
    const int tid  = threadIdx.x;
    const int lane = tid & 63;
    const int wave = tid >> 6;
    const int wr = wave >> 1, wc = wave & 1;
    const int bid = blockIdx.x;
    const int xcd = bid & 7, loc = bid >> 3;                 // loc 0..95
    const int m0 = ((xcd >> 1) * 8 + (loc & 7)) * 128;       // 32 m-tiles
    const int n0 = ((xcd & 1) * 12 + (loc >> 3)) * 128;      // 24 n-tiles
    const int lrow = lane & 15;
    const int lk8  = (lane >> 4) * 8;
    const int K = DD;

    f32x4 acc[4][4] = {};

    for (int k0 = 0; k0 < K; k0 += 32) {
        __syncthreads();
#pragma unroll
        for (int i = 0; i < 2; ++i) {
            int c   = tid + 256 * i;
            int row = c >> 2;
            int col = (c & 3) * 8;
            unsigned short* ldsA = As + (size_t)(i * 256 + wave * 64) * 8;
            unsigned short* ldsB = Bs + (size_t)(i * 256 + wave * 64) * 8;
            gload16(A  + (size_t)(m0 + row) * K + (k0 + col), ldsA);
            gload16(Bt + (size_t)(n0 + row) * K + (k0 + col), ldsB);
        }
        __syncthreads();

        const unsigned short* Ab = As + (wr * 64 + lrow) * 32 + lk8;
        const unsigned short* Bb = Bs + (wc * 64 + lrow) * 32 + lk8;
        short8 af[4], bfr[4];
#pragma unroll
        for (int m = 0; m < 4; ++m) af[m]  = *(const short8*)(Ab + m * 16 * 32);
#pragma unroll
        for (int n = 0; n < 4; ++n) bfr[n] = *(const short8*)(Bb + n * 16 * 32);
#pragma unroll
        for (int m = 0; m < 4; ++m)
#pragma unroll
            for (int n = 0; n < 4; ++n)
                acc[m][n] = __builtin_amdgcn_mfma_f32_16x16x32_bf16(af[m], bfr[n], acc[m][n], 0, 0, 0);
    }

    const int part = n0 >> 10;                       // 0=Q 1=K 2=V
    const int n0c  = n0 + wc * 64;
    const int h    = ((n0 & 1023) + wc * 64) >> 6;

    if (part < 2) {
        unsigned short* Dst = part == 0 ? Qb : Kb;
        const float qs = part == 0 ? K1ATT : 1.0f;
#pragma unroll
        for (int m = 0; m < 4; ++m)
#pragma unroll
            for (int r = 0; r < 4; ++r) {
                int gm = m0 + wr * 64 + m * 16 + (lane >> 4) * 4 + r;
                int b = gm >> 11, t = gm & (TT - 1);
                size_t rowoff = ((size_t)(b * HH + h) * TT + t) * 64;
#pragma unroll
                for (int n = 0; n < 2; ++n) {
                    int dr = n * 16 + lrow;
                    float2 c2 = cs[t * 32 + dr];
                    float lo = acc[m][n][r]     + bias[n0c + dr];
                    float hi = acc[m][n + 2][r] + bias[n0c + 32 + dr];
                    Dst[rowoff + dr]      = f2bf((lo * c2.x - hi * c2.y) * qs);
                    Dst[rowoff + 32 + dr] = f2bf((hi * c2.x + lo * c2.y) * qs);
                }
            }
    } else {
#pragma unroll
        for (int m = 0; m < 4; ++m)
#pragma unroll
            for (int r = 0; r < 4; ++r) {
                int gm = m0 + wr * 64 + m * 16 + (lane >> 4) * 4 + r;
                int b = gm >> 11, t = gm & (TT - 1);
                size_t rowoff = ((size_t)(b * HH + h) * TT + t) * 64;
#pragma unroll
                for (int n = 0; n < 4; ++n) {
                    int d = n * 16 + lrow;
                    Vrow[rowoff + d] = f2bf(acc[m][n][r] + bias[n0c + d]);
                }
            }
    }
}

// ============================================================
// output GEMM (R6-proven loop): M=4096 N=1024 K=1024.
// 1D grid 256 blocks; XCD chunk 8m x 4n.
// ============================================================
__global__ __launch_bounds__(256)
void k_gemm_bt(const unsigned short* __restrict__ A,
               const unsigned short* __restrict__ Bt,
               const float* __restrict__ bias,
               float* __restrict__ C) {
    __shared__ unsigned short As[128 * 32];
    __shared__ unsigned short Bs[128 * 32];
    const int tid  = threadIdx.x;
    const int lane = tid & 63;
    const int wave = tid >> 6;
    const int wr = wave >> 1, wc = wave & 1;
    const int bid = blockIdx.x;
    const int xcd = bid & 7, loc = bid >> 3;                 // loc 0..31
    const int m0 = ((xcd >> 1) * 8 + (loc & 7)) * 128;       // 32 m-tiles
    const int n0 = ((xcd & 1) * 4 + (loc >> 3)) * 128;       // 8 n-tiles
    const int lrow = lane & 15;
    const int lk8  = (lane >> 4) * 8;
    const int K = DD, N = DD;

    f32x4 acc[4][4] = {};

    for (int k0 = 0; k0 < K; k0 += 32) {
        __syncthreads();
#pragma unroll
        for (int i = 0; i < 2; ++i) {
            int c   = tid + 256 * i;
            int row = c >> 2;
            int col = (c & 3) * 8;
            unsigned short* ldsA = As + (size_t)(i * 256 + wave * 64) * 8;
            unsigned short* ldsB = Bs + (size_t)(i * 256 + wave * 64) * 8;
            gload16(A  + (size_t)(m0 + row) * K + (k0 + col), ldsA);
            gload16(Bt + (size_t)(n0 + row) * K + (k0 + col), ldsB);
        }
        __syncthreads();

        const unsigned short* Ab = As + (wr * 64 + lrow) * 32 + lk8;
        const unsigned short* Bb = Bs + (wc * 64 + lrow) * 32 + lk8;
        short8 af[4], bfr[4];
#pragma unroll
        for (int m = 0; m < 4; ++m) af[m]  = *(const short8*)(Ab + m * 16 * 32);
#pragma unroll
        for (int n = 0; n < 4; ++n) bfr[n] = *(const short8*)(Bb + n * 16 * 32);
#pragma unroll
        for (int m = 0; m < 4; ++m)
#pragma unroll
            for (int n = 0; n < 4; ++n)
                acc[m][n] = __builtin_amdgcn_mfma_f32_16x16x32_bf16(af[m], bfr[n], acc[m][n], 0, 0, 0);
    }

#pragma unroll
    for (int m = 0; m < 4; ++m) {
        int row = m0 + wr * 64 + m * 16 + (lane >> 4) * 4;
#pragma unroll
        for (int n = 0; n < 4; ++n) {
            int col = n0 + wc * 64 + n * 16 + lrow;
            float bv = bias[col];
#pragma unroll
            for (int r = 0; r < 4; ++r)
                C[(size_t)(row + r) * N + col] = acc[m][n][r] + bv;
        }
    }
}

// ============================================================
// V transpose (bf16): Vrow [B][H][T][64] -> Vt [B][H][64][T]
// ============================================================
__global__ void k_vtrans(const unsigned short* __restrict__ Vrow, unsigned short* __restrict__ Vt) {
    __shared__ unsigned short tile[64][66];
    int bh = blockIdx.y;
    int t0 = blockIdx.x * 64;
    int tx = threadIdx.x & 63, ty = threadIdx.x >> 6;
#pragma unroll
    for (int r = ty; r < 64; r += 4)
        tile[r][tx] = Vrow[((size_t)bh * TT + t0 + r) * 64 + tx];
    __syncthreads();
#pragma unroll
    for (int r = ty; r < 64; r += 4)
        Vt[((size_t)bh * 64 + r) * TT + t0 + tx] = tile[tx][r];
}

// ============================================================
// Flash attention, KVBLK=64 with FENCED sequential halves.
// R12's spill came from the compiler interleaving the two
// data-independent 32-key halves (live-range blowup). A single
// sched_barrier(0) between them forbids cross-half motion ->
// per-half register peak == R10's proven 64-VGPR level, while
// the __syncthreads count halves (16 MFMAs + 32 exp2 per
// barrier). SPLIT=2, 1024 blocks x 4 waves (16 waves/CU = the
// measured saturation point), XCD swizzle, fixed-max softmax.
// ============================================================
__global__ __launch_bounds__(256, 4)
void k_attn(const unsigned short* __restrict__ Q,
            const unsigned short* __restrict__ Kg,
            const unsigned short* __restrict__ Vt,
            const unsigned* __restrict__ mbits,
            float* __restrict__ Opart, float* __restrict__ lbuf) {
    __shared__ unsigned short lds[2][2][4096];   // [buf][K|V][64x64] = 32 KB
    const int tid = threadIdx.x, lane = tid & 63, wave = tid >> 6;
    // XCD swizzle: 1024 blocks, 128 per XCD
    const int bid = blockIdx.x;
    const int w   = (bid & 7) * 128 + (bid >> 3);
    const int qx  = w & 15;
    const int z   = (w >> 4) & 1;
    const int bh  = w >> 5;
    const int b   = bh >> 4;
    const int q0  = (qx * 4 + wave) * 32;
    const int lq  = lane & 31;
    const int hi  = lane >> 5;
    const int k0  = z * KVLEN;

    const unsigned short* Qp = Q  + ((size_t)bh * TT + q0) * 64;
    const unsigned short* Kp = Kg + (size_t)bh * TT * 64 + (size_t)k0 * 64;
    const unsigned short* Vp = Vt + (size_t)bh * 64 * TT + k0;

    // 32 mask words (32 keys each) for this split, lane-indexed
    unsigned mwv = mbits[b * 64 + z * 32 + lq];

    // staging geometry: lane stages rows c*32 + rr8 (c=0,1); the
    // swizzle index jj is c-invariant (32 == 0 mod 8).
    const int rr8 = wave * 8 + (lane >> 3);
    const int jj  = (lane & 7) ^ (rr8 & 7);

    // Q fragments: col q = lq, d = c*16 + hi*8 + e
    short8 qf[4];
#pragma unroll
    for (int c = 0; c < 4; ++c)
        qf[c] = *(const short8*)(Qp + lq * 64 + c * 16 + hi * 8);

    f32x16 o0 = {}, o1 = {};
    float lhalf = 0.f;
    const int rx = lq & 7;

    auto stage = [&](int tt, int buf) {
#pragma unroll
        for (int c = 0; c < 2; ++c) {
            int row = c * 32 + rr8;
            gload16(Kp + (size_t)(tt * 64 + row) * 64 + jj * 8,
                    &lds[buf][0][(c * 32 + wave * 8) * 64]);
            gload16(Vp + (size_t)row * TT + tt * 64 + jj * 8,
                    &lds[buf][1][(c * 32 + wave * 8) * 64]);
        }
    };

    // one complete 32-key pipeline; h = half (0: keys 0-31, 1: 32-63)
    auto half_compute = [&](const unsigned short* Kl, const unsigned short* Vl,
                            int h, unsigned mw) {
        const unsigned short* kb = Kl + (h * 32 + lq) * 64;
        short8 kf0 = *(const short8*)(kb + ((0 + hi) ^ rx) * 8);
        short8 kf1 = *(const short8*)(kb + ((2 + hi) ^ rx) * 8);
        short8 kf2 = *(const short8*)(kb + ((4 + hi) ^ rx) * 8);
        short8 kf3 = *(const short8*)(kb + ((6 + hi) ^ rx) * 8);

        f32x16 s = {};
        __builtin_amdgcn_s_setprio(1);
        s = __builtin_amdgcn_mfma_f32_32x32x16_bf16(kf0, qf[0], s, 0, 0, 0);
        s = __builtin_amdgcn_mfma_f32_32x32x16_bf16(kf1, qf[1], s, 0, 0, 0);
        s = __builtin_amdgcn_mfma_f32_32x32x16_bf16(kf2, qf[2], s, 0, 0, 0);
        s = __builtin_amdgcn_mfma_f32_32x32x16_bf16(kf3, qf[3], s, 0, 0, 0);
        __builtin_amdgcn_s_setprio(0);

        float p[16];
        if (mw) {                                   // wave-uniform rare path
            unsigned bmh = mw >> (hi * 4);
#pragma unroll
            for (int r = 0; r < 16; ++r) {
                float v = s[r];
                if ((bmh >> ((r & 3) + 8 * (r >> 2))) & 1u) v = -INFINITY;
                p[r] = __builtin_amdgcn_exp2f(v);
            }
        } else {
#pragma unroll
            for (int r = 0; r < 16; ++r) p[r] = __builtin_amdgcn_exp2f(s[r]);
        }

        float ts[8];
#pragma unroll
        for (int r = 0; r < 8; ++r) ts[r] = p[r] + p[r + 8];
#pragma unroll
        for (int r = 0; r < 4; ++r) ts[r] = ts[r] + ts[r + 4];
        lhalf += (ts[0] + ts[1]) + (ts[2] + ts[3]);

        unsigned u[8];
#pragma unroll
        for (int i = 0; i < 8; ++i) u[i] = cvt_pk_bf16(p[2 * i], p[2 * i + 1]);

        unsigned s0 = hi ? u[0] : u[2];
        unsigned s1 = hi ? u[1] : u[3];
        unsigned s2 = hi ? u[4] : u[6];
        unsigned s3 = hi ? u[5] : u[7];
        unsigned r0 = __shfl_xor(s0, 32, 64);
        unsigned r1 = __shfl_xor(s1, 32, 64);
        unsigned r2 = __shfl_xor(s2, 32, 64);
        unsigned r3 = __shfl_xor(s3, 32, 64);

        union { unsigned w[4]; short8 v; } a0, a1;
        a0.w[0] = hi ? r0 : u[0];
        a0.w[1] = hi ? r1 : u[1];
        a0.w[2] = hi ? u[2] : r0;
        a0.w[3] = hi ? u[3] : r1;
        a1.w[0] = hi ? r2 : u[4];
        a1.w[1] = hi ? r3 : u[5];
        a1.w[2] = hi ? u[6] : r2;
        a1.w[3] = hi ? u[7] : r3;

        // V chunks for this half: key-chunk base h*4 within the 64-key row
        const unsigned short* vb0 = Vl + lq * 64;          // d = lq
        const unsigned short* vb1 = Vl + (32 + lq) * 64;   // d = 32+lq
        short8 vf00 = *(const short8*)(vb0 + ((h * 4 + 0 + hi) ^ rx) * 8);
        short8 vf10 = *(const short8*)(vb0 + ((h * 4 + 2 + hi) ^ rx) * 8);
        short8 vf01 = *(const short8*)(vb1 + ((h * 4 + 0 + hi) ^ rx) * 8);
        short8 vf11 = *(const short8*)(vb1 + ((h * 4 + 2 + hi) ^ rx) * 8);

        __builtin_amdgcn_s_setprio(1);
        o0 = __builtin_amdgcn_mfma_f32_32x32x16_bf16(a0.v, vf00, o0, 0, 0, 0);
        o0 = __builtin_amdgcn_mfma_f32_32x32x16_bf16(a1.v, vf10, o0, 0, 0, 0);
        o1 = __builtin_amdgcn_mfma_f32_32x32x16_bf16(a0.v, vf01, o1, 0, 0, 0);
        o1 = __builtin_amdgcn_mfma_f32_32x32x16_bf16(a1.v, vf11, o1, 0, 0, 0);
        __builtin_amdgcn_s_setprio(0);
    };

    auto tile_compute = [&](const unsigned short* Kl, const unsigned short* Vl, int t) {
        unsigned mw0 = __builtin_amdgcn_readlane(mwv, 2 * t);
        unsigned mw1 = __builtin_amdgcn_readlane(mwv, 2 * t + 1);
        half_compute(Kl, Vl, 0, mw0);
        // FENCE: forbid interleaving of the two halves (R12 spilled
        // because the scheduler merged their live ranges).
        __builtin_amdgcn_sched_barrier(0);
        half_compute(Kl, Vl, 1, mw1);
    };

    // prologue
    stage(0, 0);
    __syncthreads();

    for (int t = 0; t < NTILE; t += 2) {
        stage(t + 1, 1);
        tile_compute(&lds[0][0][0], &lds[0][1][0], t);
        __syncthreads();
        if (t + 2 < NTILE) stage(t + 2, 0);
        tile_compute(&lds[1][0][0], &lds[1][1][0], t + 1);
        __syncthreads();
    }

    // epilogue
    float ltot = lhalf + __shfl_xor(lhalf, 32, 64);
#pragma unroll
    for (int r = 0; r < 16; ++r) {
        int qrow = (r & 3) + 8 * (r >> 2) + 4 * hi;
        size_t row = (size_t)z * NROWS + (size_t)bh * TT + q0 + qrow;
        float* Orow = Opart + row * 64;
        Orow[lq]      = o0[r];
        Orow[32 + lq] = o1[r];
    }
    if (hi == 0)
        lbuf[(size_t)z * NROWS + (size_t)bh * TT + q0 + lq] = ltot;
}

// ============================================================
// combine 2 splits (fixed max): out = (O1+O2)/(l1+l2)
// ============================================================
__global__ void k_combine(const float* __restrict__ Opart, const float* __restrict__ lbuf,
                          unsigned short* __restrict__ Ob) {
    int i = blockIdx.x * 256 + threadIdx.x;
    int g  = i >> 4;
    int d4 = (i & 15) * 4;
    f32x4 va = *(const f32x4*)(Opart + (size_t)g * 64 + d4);
    f32x4 vb = *(const f32x4*)(Opart + ((size_t)NROWS + g) * 64 + d4);
    float inv = 1.0f / (lbuf[g] + lbuf[NROWS + g]);
    int bh = g >> 11, t = g & (TT - 1), bb = bh >> 4, h = bh & 15;
    unsigned short* orow = Ob + ((size_t)(bb * TT + t)) * DD + h * 64 + d4;
#pragma unroll
    for (int jj = 0; jj < 4; ++jj)
        orow[jj] = f2bf((va[jj] + vb[jj]) * inv);
}

// ============================================================
// launch — workspace aliasing: Opart region hosts xb/wqkvt/
// Vrow/cs (dead pre-attn); Ob aliases Qb (dead post-attn).
// ============================================================
extern "C" void kernel_launch(void* const* d_in, const int* in_sizes, int n_in,
                              void* d_out, int out_size, void* d_ws, size_t ws_size,
                              hipStream_t stream) {
    const float* x      = (const float*)d_in[0];
    const float* W_qkv  = (const float*)d_in[1];
    const float* b_qkv  = (const float*)d_in[2];
    const float* W_out  = (const float*)d_in[3];
    const float* b_out  = (const float*)d_in[4];
    const unsigned char* mask = (const unsigned char*)d_in[5];
    float* out = (float*)d_out;

    char* ws = (char*)d_ws;
    size_t off = 0;
    auto alloc = [&](size_t bytes) { char* p = ws + off; off += (bytes + 255) & ~(size_t)255; return p; };

    float* Opart = (float*)alloc((size_t)SPLIT * NROWS * 64 * 4);      // 33.6 MB
    unsigned short* xb    = (unsigned short*)((char*)Opart);
    unsigned short* wqkvt = (unsigned short*)((char*)Opart + (8u << 20));
    unsigned short* Vrow  = (unsigned short*)((char*)Opart + (14u << 20));
    float2*         cs    = (float2*)        ((char*)Opart + (23u << 20));

    unsigned short* woutt = (unsigned short*)alloc((size_t)DD * DD * 2);
    unsigned short* Qb    = (unsigned short*)alloc((size_t)BB * HH * TT * HDIM * 2);
    unsigned short* Kb    = (unsigned short*)alloc((size_t)BB * HH * TT * HDIM * 2);
    unsigned short* Vtb   = (unsigned short*)alloc((size_t)BB * HH * TT * HDIM * 2);
    float*          lbuf  = (float*)         alloc((size_t)SPLIT * NROWS * 4);
    unsigned*       mbits = (unsigned*)      alloc((size_t)BB * 64 * 4);
    unsigned short* Ob    = Qb;   // Qb dead after attn

    // 1. fused prep
    k_prep<<<5377, 256, 0, stream>>>(x, W_qkv, W_out, mask, xb, cs, wqkvt, woutt, mbits);
    // 2. QKV GEMM with fused bias+RoPE+scatter
    k_gemm_qkv<<<768, 256, 0, stream>>>(xb, wqkvt, b_qkv, cs, Qb, Kb, Vrow);
    // 3. V transpose (bf16)
    {
        dim3 g(TT / 64, BB * HH);
        k_vtrans<<<g, 256, 0, stream>>>(Vrow, Vtb);
    }
    // 4. attention: 1024 blocks, 2-way KV split, 64-key tiles (fenced halves)
    k_attn<<<dim3(16 * BB * HH * SPLIT), 256, 0, stream>>>(Qb, Kb, Vtb, mbits, Opart, lbuf);
    {
        dim3 g((NROWS * 16) / 256);
        k_combine<<<g, 256, 0, stream>>>(Opart, lbuf, Ob);
    }
    // 5. output GEMM
    k_gemm_bt<<<256, 256, 0, stream>>>(Ob, woutt, b_out, out);
}

// Round 16
// 141.575 us; speedup vs baseline: 1.1643x; 1.1643x over previous
//
#include <hip/hip_runtime.h>
#include <hip/hip_bf16.h>
#include <math.h>

#define DEV_INLINE __device__ __forceinline__

typedef __attribute__((ext_vector_type(4))) float f32x4;
typedef __attribute__((ext_vector_type(16))) float f32x16;
typedef __attribute__((ext_vector_type(8))) short short8;
typedef __attribute__((ext_vector_type(4))) unsigned short u16x4;

// ---------- bf16 helpers ----------
DEV_INLINE unsigned short f2bf(float f) {
    unsigned int u = __builtin_bit_cast(unsigned int, f);
    u += 0x7FFFu + ((u >> 16) & 1u);   // round-to-nearest-even
    return (unsigned short)(u >> 16);
}
DEV_INLINE unsigned cvt_pk_bf16(float lo, float hi) {
    unsigned r;
    asm("v_cvt_pk_bf16_f32 %0, %1, %2" : "=v"(r) : "v"(lo), "v"(hi));
    return r;
}

// ---------- async global->LDS (16B per lane) ----------
DEV_INLINE void gload16(const void* g, void* l) {
    __builtin_amdgcn_global_load_lds(
        (const __attribute__((address_space(1))) unsigned int*)g,
        (__attribute__((address_space(3))) unsigned int*)l, 16, 0, 0);
}

// ---------- constants ----------
#define BB 2
#define TT 2048
#define DD 1024
#define HH 16
#define HDIM 64
#define BT (BB*TT)        // 4096
#define N3 (3*DD)         // 3072
#define NROWS (BB*HH*TT)  // 65536 attention rows
#define K1ATT 0.18033688011112042f   // (1/8) * log2(e), folded into Q

#define SPLIT 2
#define KVLEN (TT/SPLIT)   // 1024 keys per split
#define NTILE (KVLEN/32)   // 32 tiles per split

// ============================================================
// Fused prep kernel (block-range dispatch)
// ============================================================
DEV_INLINE void do_transpose(const float* __restrict__ in, unsigned short* __restrict__ out,
                             int K, int N, int bx, float (*tile)[66], int tid) {
    int nb = N >> 6;
    int n0 = (bx % nb) * 64, k0 = (bx / nb) * 64;
    int tx = tid & 63, ty = tid >> 6;
#pragma unroll
    for (int r = ty; r < 64; r += 4)
        tile[r][tx] = in[(size_t)(k0 + r) * N + n0 + tx];
    __syncthreads();
#pragma unroll
    for (int r = ty; r < 64; r += 4)
        out[(size_t)(n0 + r) * K + k0 + tx] = f2bf(tile[tx][r]);
}

__global__ __launch_bounds__(256)
void k_prep(const float* __restrict__ x, const float* __restrict__ W_qkv,
            const float* __restrict__ W_out, const unsigned char* __restrict__ mask,
            unsigned short* __restrict__ xb, float2* __restrict__ cs,
            unsigned short* __restrict__ wqkvt, unsigned short* __restrict__ woutt,
            unsigned* __restrict__ mbits) {
    __shared__ float tile[64][66];
    const int bid = blockIdx.x, tid = threadIdx.x;
    if (bid < 4096) {
        int i = bid * 256 + tid;
        f32x4 v = ((const f32x4*)x)[i];
        u16x4 o;
        o[0] = f2bf(v[0]); o[1] = f2bf(v[1]); o[2] = f2bf(v[2]); o[3] = f2bf(v[3]);
        ((u16x4*)xb)[i] = o;
    } else if (bid < 4352) {
        int i = (bid - 4096) * 256 + tid;
        int t = i >> 5, f = i & 31;
        float inv = powf(10000.0f, -(float)f / 32.0f);
        float ang = (float)t * inv;
        cs[i] = make_float2(cosf(ang), sinf(ang));
    } else if (bid < 5120) {
        do_transpose(W_qkv, wqkvt, DD, N3, bid - 4352, tile, tid);
    } else if (bid < 5376) {
        do_transpose(W_out, woutt, DD, DD, bid - 5120, tile, tid);
    } else {
        if (tid < BB * 64) {
            int b = tid >> 6, w = tid & 63;
            unsigned v = 0;
#pragma unroll
            for (int j = 0; j < 32; ++j)
                v |= (mask[b * TT + w * 32 + j] ? 1u : 0u) << j;
            mbits[tid] = v;
        }
    }
}

// ============================================================
// QKV GEMM + fused bias + RoPE + scatter (R6-proven loop).
// 1D grid, 2D XCD chunk: 8 XCDs as 4(m)x2(n).
// ============================================================
__global__ __launch_bounds__(256)
void k_gemm_qkv(const unsigned short* __restrict__ A,
                const unsigned short* __restrict__ Bt,
                const float* __restrict__ bias,
                const float2* __restrict__ cs,
                unsigned short* __restrict__ Qb,
                unsigned short* __restrict__ Kb,
                unsigned short* __restrict__ Vrow) {
    __shared__ unsigned short As[128 * 32];
    __shared__ unsigned short Bs[128 * 32];
    const int tid  = threadIdx.x;
    const int lane = tid & 63;
    const int wave = tid >> 6;
    const int wr = wave >> 1, wc = wave & 1;
    const int bid = blockIdx.x;
    const int xcd = bid & 7, loc = bid >> 3;                 // loc 0..95
    const int m0 = ((xcd >> 1) * 8 + (loc & 7)) * 128;       // 32 m-tiles
    const int n0 = ((xcd & 1) * 12 + (loc >> 3)) * 128;      // 24 n-tiles
    const int lrow = lane & 15;
    const int lk8  = (lane >> 4) * 8;
    const int K = DD;

    f32x4 acc[4][4] = {};

    for (int k0 = 0; k0 < K; k0 += 32) {
        __syncthreads();
#pragma unroll
        for (int i = 0; i < 2; ++i) {
            int c   = tid + 256 * i;
            int row = c >> 2;
            int col = (c & 3) * 8;
            unsigned short* ldsA = As + (size_t)(i * 256 + wave * 64) * 8;
            unsigned short* ldsB = Bs + (size_t)(i * 256 + wave * 64) * 8;
            gload16(A  + (size_t)(m0 + row) * K + (k0 + col), ldsA);
            gload16(Bt + (size_t)(n0 + row) * K + (k0 + col), ldsB);
        }
        __syncthreads();

        const unsigned short* Ab = As + (wr * 64 + lrow) * 32 + lk8;
        const unsigned short* Bb = Bs + (wc * 64 + lrow) * 32 + lk8;
        short8 af[4], bfr[4];
#pragma unroll
        for (int m = 0; m < 4; ++m) af[m]  = *(const short8*)(Ab + m * 16 * 32);
#pragma unroll
        for (int n = 0; n < 4; ++n) bfr[n] = *(const short8*)(Bb + n * 16 * 32);
#pragma unroll
        for (int m = 0; m < 4; ++m)
#pragma unroll
            for (int n = 0; n < 4; ++n)
                acc[m][n] = __builtin_amdgcn_mfma_f32_16x16x32_bf16(af[m], bfr[n], acc[m][n], 0, 0, 0);
    }

    const int part = n0 >> 10;                       // 0=Q 1=K 2=V
    const int n0c  = n0 + wc * 64;
    const int h    = ((n0 & 1023) + wc * 64) >> 6;

    if (part < 2) {
        unsigned short* Dst = part == 0 ? Qb : Kb;
        const float qs = part == 0 ? K1ATT : 1.0f;
#pragma unroll
        for (int m = 0; m < 4; ++m)
#pragma unroll
            for (int r = 0; r < 4; ++r) {
                int gm = m0 + wr * 64 + m * 16 + (lane >> 4) * 4 + r;
                int b = gm >> 11, t = gm & (TT - 1);
                size_t rowoff = ((size_t)(b * HH + h) * TT + t) * 64;
#pragma unroll
                for (int n = 0; n < 2; ++n) {
                    int dr = n * 16 + lrow;
                    float2 c2 = cs[t * 32 + dr];
                    float lo = acc[m][n][r]     + bias[n0c + dr];
                    float hi = acc[m][n + 2][r] + bias[n0c + 32 + dr];
                    Dst[rowoff + dr]      = f2bf((lo * c2.x - hi * c2.y) * qs);
                    Dst[rowoff + 32 + dr] = f2bf((hi * c2.x + lo * c2.y) * qs);
                }
            }
    } else {
#pragma unroll
        for (int m = 0; m < 4; ++m)
#pragma unroll
            for (int r = 0; r < 4; ++r) {
                int gm = m0 + wr * 64 + m * 16 + (lane >> 4) * 4 + r;
                int b = gm >> 11, t = gm & (TT - 1);
                size_t rowoff = ((size_t)(b * HH + h) * TT + t) * 64;
#pragma unroll
                for (int n = 0; n < 4; ++n) {
                    int d = n * 16 + lrow;
                    Vrow[rowoff + d] = f2bf(acc[m][n][r] + bias[n0c + d]);
                }
            }
    }
}

// ============================================================
// output GEMM (R6-proven loop): M=4096 N=1024 K=1024.
// 1D grid 256 blocks; XCD chunk 8m x 4n.
// ============================================================
__global__ __launch_bounds__(256)
void k_gemm_bt(const unsigned short* __restrict__ A,
               const unsigned short* __restrict__ Bt,
               const float* __restrict__ bias,
               float* __restrict__ C) {
    __shared__ unsigned short As[128 * 32];
    __shared__ unsigned short Bs[128 * 32];
    const int tid  = threadIdx.x;
    const int lane = tid & 63;
    const int wave = tid >> 6;
    const int wr = wave >> 1, wc = wave & 1;
    const int bid = blockIdx.x;
    const int xcd = bid & 7, loc = bid >> 3;                 // loc 0..31
    const int m0 = ((xcd >> 1) * 8 + (loc & 7)) * 128;       // 32 m-tiles
    const int n0 = ((xcd & 1) * 4 + (loc >> 3)) * 128;       // 8 n-tiles
    const int lrow = lane & 15;
    const int lk8  = (lane >> 4) * 8;
    const int K = DD, N = DD;

    f32x4 acc[4][4] = {};

    for (int k0 = 0; k0 < K; k0 += 32) {
        __syncthreads();
#pragma unroll
        for (int i = 0; i < 2; ++i) {
            int c   = tid + 256 * i;
            int row = c >> 2;
            int col = (c & 3) * 8;
            unsigned short* ldsA = As + (size_t)(i * 256 + wave * 64) * 8;
            unsigned short* ldsB = Bs + (size_t)(i * 256 + wave * 64) * 8;
            gload16(A  + (size_t)(m0 + row) * K + (k0 + col), ldsA);
            gload16(Bt + (size_t)(n0 + row) * K + (k0 + col), ldsB);
        }
        __syncthreads();

        const unsigned short* Ab = As + (wr * 64 + lrow) * 32 + lk8;
        const unsigned short* Bb = Bs + (wc * 64 + lrow) * 32 + lk8;
        short8 af[4], bfr[4];
#pragma unroll
        for (int m = 0; m < 4; ++m) af[m]  = *(const short8*)(Ab + m * 16 * 32);
#pragma unroll
        for (int n = 0; n < 4; ++n) bfr[n] = *(const short8*)(Bb + n * 16 * 32);
#pragma unroll
        for (int m = 0; m < 4; ++m)
#pragma unroll
            for (int n = 0; n < 4; ++n)
                acc[m][n] = __builtin_amdgcn_mfma_f32_16x16x32_bf16(af[m], bfr[n], acc[m][n], 0, 0, 0);
    }

#pragma unroll
    for (int m = 0; m < 4; ++m) {
        int row = m0 + wr * 64 + m * 16 + (lane >> 4) * 4;
#pragma unroll
        for (int n = 0; n < 4; ++n) {
            int col = n0 + wc * 64 + n * 16 + lrow;
            float bv = bias[col];
#pragma unroll
            for (int r = 0; r < 4; ++r)
                C[(size_t)(row + r) * N + col] = acc[m][n][r] + bv;
        }
    }
}

// ============================================================
// V transpose (bf16): Vrow [B][H][T][64] -> Vt [B][H][64][T]
// ============================================================
__global__ void k_vtrans(const unsigned short* __restrict__ Vrow, unsigned short* __restrict__ Vt) {
    __shared__ unsigned short tile[64][66];
    int bh = blockIdx.y;
    int t0 = blockIdx.x * 64;
    int tx = threadIdx.x & 63, ty = threadIdx.x >> 6;
#pragma unroll
    for (int r = ty; r < 64; r += 4)
        tile[r][tx] = Vrow[((size_t)bh * TT + t0 + r) * 64 + tx];
    __syncthreads();
#pragma unroll
    for (int r = ty; r < 64; r += 4)
        Vt[((size_t)bh * 64 + r) * TT + t0 + tx] = tile[tx][r];
}

// ============================================================
// Flash attention (R10/R13-proven structure, KVBLK=32): swapped-
// QK^T 32x32, LDS dbuf K/V (__syncthreads 2-phase), fixed-max
// softmax, SPLIT=2 (1024 blocks), XCD-swizzled grid.
// launch_bounds(256,4): natural VGPR ~64, no spill.
// KVBLK=64 is falsified 3 ways (R11 concurrent, R12 sequential,
// R15 fenced): its ~130 live VGPRs exceed the (256,4) budget of
// 128 regardless of scheduling -> scratch spill. Do not retry.
// ============================================================
__global__ __launch_bounds__(256, 4)
void k_attn(const unsigned short* __restrict__ Q,
            const unsigned short* __restrict__ Kg,
            const unsigned short* __restrict__ Vt,
            const unsigned* __restrict__ mbits,
            float* __restrict__ Opart, float* __restrict__ lbuf) {
    __shared__ unsigned short lds[2][2][2048];   // [buf][K/V][32x64]
    const int tid = threadIdx.x, lane = tid & 63, wave = tid >> 6;
    // XCD swizzle: 1024 blocks, 128 per XCD
    const int bid = blockIdx.x;
    const int w   = (bid & 7) * 128 + (bid >> 3);
    const int qx  = w & 15;
    const int z   = (w >> 4) & 1;
    const int bh  = w >> 5;
    const int b   = bh >> 4;
    const int q0  = (qx * 4 + wave) * 32;
    const int lq  = lane & 31;
    const int hi  = lane >> 5;
    const int k0  = z * KVLEN;

    const unsigned short* Qp = Q  + ((size_t)bh * TT + q0) * 64;
    const unsigned short* Kp = Kg + (size_t)bh * TT * 64 + (size_t)k0 * 64;
    const unsigned short* Vp = Vt + (size_t)bh * 64 * TT + k0;

    // 32 mask words for this split, lane-indexed (readlane per tile)
    unsigned mwv = mbits[b * 64 + z * 32 + lq];

    // staging geometry (inverse-swizzled source, linear LDS dest)
    const int rr = wave * 8 + (lane >> 3);
    const int j  = (lane & 7) ^ (rr & 7);
    const size_t ksrc = (size_t)rr * 64 + j * 8;
    const int vd = rr + ((j >> 2) << 5);
    const size_t vsrc = (size_t)vd * TT + (j & 3) * 8;

    // Q fragments: col q = lq, d = c*16 + hi*8 + e
    short8 qf[4];
#pragma unroll
    for (int c = 0; c < 4; ++c)
        qf[c] = *(const short8*)(Qp + lq * 64 + c * 16 + hi * 8);

    f32x16 o0 = {}, o1 = {};
    float lhalf = 0.f;
    const int rx = lq & 7;

    auto stage = [&](int tt, int buf) {
        gload16(Kp + (size_t)tt * 32 * 64 + ksrc, &lds[buf][0][wave * 512]);
        gload16(Vp + tt * 32 + vsrc,              &lds[buf][1][wave * 512]);
    };

    auto tile_compute = [&](const unsigned short* Kl, const unsigned short* Vl, int t) {
        short8 kf0 = *(const short8*)(Kl + lq * 64 + ((0 + hi) ^ rx) * 8);
        short8 kf1 = *(const short8*)(Kl + lq * 64 + ((2 + hi) ^ rx) * 8);
        short8 kf2 = *(const short8*)(Kl + lq * 64 + ((4 + hi) ^ rx) * 8);
        short8 kf3 = *(const short8*)(Kl + lq * 64 + ((6 + hi) ^ rx) * 8);
        short8 vf00 = *(const short8*)(Vl + lq * 64 + ((0 + hi) ^ rx) * 8);
        short8 vf10 = *(const short8*)(Vl + lq * 64 + ((2 + hi) ^ rx) * 8);
        short8 vf01 = *(const short8*)(Vl + lq * 64 + ((4 + hi) ^ rx) * 8);
        short8 vf11 = *(const short8*)(Vl + lq * 64 + ((6 + hi) ^ rx) * 8);

        f32x16 s = {};
        __builtin_amdgcn_s_setprio(1);
        s = __builtin_amdgcn_mfma_f32_32x32x16_bf16(kf0, qf[0], s, 0, 0, 0);
        s = __builtin_amdgcn_mfma_f32_32x32x16_bf16(kf1, qf[1], s, 0, 0, 0);
        s = __builtin_amdgcn_mfma_f32_32x32x16_bf16(kf2, qf[2], s, 0, 0, 0);
        s = __builtin_amdgcn_mfma_f32_32x32x16_bf16(kf3, qf[3], s, 0, 0, 0);
        __builtin_amdgcn_s_setprio(0);

        unsigned mw = __builtin_amdgcn_readlane(mwv, t);
        float p[16];
        if (mw) {                                   // wave-uniform rare path
            unsigned bmh = mw >> (hi * 4);
#pragma unroll
            for (int r = 0; r < 16; ++r) {
                float v = s[r];
                if ((bmh >> ((r & 3) + 8 * (r >> 2))) & 1u) v = -INFINITY;
                p[r] = __builtin_amdgcn_exp2f(v);
            }
        } else {
#pragma unroll
            for (int r = 0; r < 16; ++r) p[r] = __builtin_amdgcn_exp2f(s[r]);
        }

        float ts[8];
#pragma unroll
        for (int r = 0; r < 8; ++r) ts[r] = p[r] + p[r + 8];
#pragma unroll
        for (int r = 0; r < 4; ++r) ts[r] = ts[r] + ts[r + 4];
        lhalf += (ts[0] + ts[1]) + (ts[2] + ts[3]);

        unsigned u[8];
#pragma unroll
        for (int i = 0; i < 8; ++i) u[i] = cvt_pk_bf16(p[2 * i], p[2 * i + 1]);

        unsigned s0 = hi ? u[0] : u[2];
        unsigned s1 = hi ? u[1] : u[3];
        unsigned s2 = hi ? u[4] : u[6];
        unsigned s3 = hi ? u[5] : u[7];
        unsigned r0 = __shfl_xor(s0, 32, 64);
        unsigned r1 = __shfl_xor(s1, 32, 64);
        unsigned r2 = __shfl_xor(s2, 32, 64);
        unsigned r3 = __shfl_xor(s3, 32, 64);

        union { unsigned w[4]; short8 v; } a0, a1;
        a0.w[0] = hi ? r0 : u[0];
        a0.w[1] = hi ? r1 : u[1];
        a0.w[2] = hi ? u[2] : r0;
        a0.w[3] = hi ? u[3] : r1;
        a1.w[0] = hi ? r2 : u[4];
        a1.w[1] = hi ? r3 : u[5];
        a1.w[2] = hi ? u[6] : r2;
        a1.w[3] = hi ? u[7] : r3;

        __builtin_amdgcn_s_setprio(1);
        o0 = __builtin_amdgcn_mfma_f32_32x32x16_bf16(a0.v, vf00, o0, 0, 0, 0);
        o0 = __builtin_amdgcn_mfma_f32_32x32x16_bf16(a1.v, vf10, o0, 0, 0, 0);
        o1 = __builtin_amdgcn_mfma_f32_32x32x16_bf16(a0.v, vf01, o1, 0, 0, 0);
        o1 = __builtin_amdgcn_mfma_f32_32x32x16_bf16(a1.v, vf11, o1, 0, 0, 0);
        __builtin_amdgcn_s_setprio(0);
    };

    // prologue
    stage(0, 0);
    __syncthreads();

    for (int t = 0; t < NTILE; t += 2) {
        stage(t + 1, 1);
        tile_compute(&lds[0][0][0], &lds[0][1][0], t);
        __syncthreads();
        if (t + 2 < NTILE) stage(t + 2, 0);
        tile_compute(&lds[1][0][0], &lds[1][1][0], t + 1);
        __syncthreads();
    }

    // epilogue
    float ltot = lhalf + __shfl_xor(lhalf, 32, 64);
#pragma unroll
    for (int r = 0; r < 16; ++r) {
        int qrow = (r & 3) + 8 * (r >> 2) + 4 * hi;
        size_t row = (size_t)z * NROWS + (size_t)bh * TT + q0 + qrow;
        float* Orow = Opart + row * 64;
        Orow[lq]      = o0[r];
        Orow[32 + lq] = o1[r];
    }
    if (hi == 0)
        lbuf[(size_t)z * NROWS + (size_t)bh * TT + q0 + lq] = ltot;
}

// ============================================================
// combine 2 splits (fixed max): out = (O1+O2)/(l1+l2)
// ============================================================
__global__ void k_combine(const float* __restrict__ Opart, const float* __restrict__ lbuf,
                          unsigned short* __restrict__ Ob) {
    int i = blockIdx.x * 256 + threadIdx.x;
    int g  = i >> 4;
    int d4 = (i & 15) * 4;
    f32x4 va = *(const f32x4*)(Opart + (size_t)g * 64 + d4);
    f32x4 vb = *(const f32x4*)(Opart + ((size_t)NROWS + g) * 64 + d4);
    float inv = 1.0f / (lbuf[g] + lbuf[NROWS + g]);
    int bh = g >> 11, t = g & (TT - 1), bb = bh >> 4, h = bh & 15;
    unsigned short* orow = Ob + ((size_t)(bb * TT + t)) * DD + h * 64 + d4;
#pragma unroll
    for (int jj = 0; jj < 4; ++jj)
        orow[jj] = f2bf((va[jj] + vb[jj]) * inv);
}

// ============================================================
// launch — workspace aliasing: Opart region hosts xb/wqkvt/
// Vrow/cs (dead pre-attn); Ob aliases Qb (dead post-attn).
// ============================================================
extern "C" void kernel_launch(void* const* d_in, const int* in_sizes, int n_in,
                              void* d_out, int out_size, void* d_ws, size_t ws_size,
                              hipStream_t stream) {
    const float* x      = (const float*)d_in[0];
    const float* W_qkv  = (const float*)d_in[1];
    const float* b_qkv  = (const float*)d_in[2];
    const float* W_out  = (const float*)d_in[3];
    const float* b_out  = (const float*)d_in[4];
    const unsigned char* mask = (const unsigned char*)d_in[5];
    float* out = (float*)d_out;

    char* ws = (char*)d_ws;
    size_t off = 0;
    auto alloc = [&](size_t bytes) { char* p = ws + off; off += (bytes + 255) & ~(size_t)255; return p; };

    float* Opart = (float*)alloc((size_t)SPLIT * NROWS * 64 * 4);      // 33.6 MB
    unsigned short* xb    = (unsigned short*)((char*)Opart);
    unsigned short* wqkvt = (unsigned short*)((char*)Opart + (8u << 20));
    unsigned short* Vrow  = (unsigned short*)((char*)Opart + (14u << 20));
    float2*         cs    = (float2*)        ((char*)Opart + (23u << 20));

    unsigned short* woutt = (unsigned short*)alloc((size_t)DD * DD * 2);
    unsigned short* Qb    = (unsigned short*)alloc((size_t)BB * HH * TT * HDIM * 2);
    unsigned short* Kb    = (unsigned short*)alloc((size_t)BB * HH * TT * HDIM * 2);
    unsigned short* Vtb   = (unsigned short*)alloc((size_t)BB * HH * TT * HDIM * 2);
    float*          lbuf  = (float*)         alloc((size_t)SPLIT * NROWS * 4);
    unsigned*       mbits = (unsigned*)      alloc((size_t)BB * 64 * 4);
    unsigned short* Ob    = Qb;   // Qb dead after attn

    // 1. fused prep
    k_prep<<<5377, 256, 0, stream>>>(x, W_qkv, W_out, mask, xb, cs, wqkvt, woutt, mbits);
    // 2. QKV GEMM with fused bias+RoPE+scatter
    k_gemm_qkv<<<768, 256, 0, stream>>>(xb, wqkvt, b_qkv, cs, Qb, Kb, Vrow);
    // 3. V transpose (bf16)
    {
        dim3 g(TT / 64, BB * HH);
        k_vtrans<<<g, 256, 0, stream>>>(Vrow, Vtb);
    }
    // 4. attention: 1024 blocks, 2-way KV split
    k_attn<<<dim3(16 * BB * HH * SPLIT), 256, 0, stream>>>(Qb, Kb, Vtb, mbits, Opart, lbuf);
    {
        dim3 g((NROWS * 16) / 256);
        k_combine<<<g, 256, 0, stream>>>(Opart, lbuf, Ob);
    }
    // 5. output GEMM
    k_gemm_bt<<<256, 256, 0, stream>>>(Ob, woutt, b_out, out);
}

// Round 17
// 138.900 us; speedup vs baseline: 1.1867x; 1.0193x over previous
//
#include <hip/hip_runtime.h>
#include <hip/hip_bf16.h>
#include <math.h>

#define DEV_INLINE __device__ __forceinline__

typedef __attribute__((ext_vector_type(4))) float f32x4;
typedef __attribute__((ext_vector_type(16))) float f32x16;
typedef __attribute__((ext_vector_type(8))) short short8;
typedef __attribute__((ext_vector_type(4))) unsigned short u16x4;

// ---------- bf16 helpers ----------
DEV_INLINE unsigned short f2bf(float f) {
    unsigned int u = __builtin_bit_cast(unsigned int, f);
    u += 0x7FFFu + ((u >> 16) & 1u);   // round-to-nearest-even
    return (unsigned short)(u >> 16);
}
DEV_INLINE unsigned cvt_pk_bf16(float lo, float hi) {
    unsigned r;
    asm("v_cvt_pk_bf16_f32 %0, %1, %2" : "=v"(r) : "v"(lo), "v"(hi));
    return r;
}

// ---------- async global->LDS (16B per lane) ----------
DEV_INLINE void gload16(const void* g, void* l) {
    __builtin_amdgcn_global_load_lds(
        (const __attribute__((address_space(1))) unsigned int*)g,
        (__attribute__((address_space(3))) unsigned int*)l, 16, 0, 0);
}

// ---------- constants ----------
#define BB 2
#define TT 2048
#define DD 1024
#define HH 16
#define HDIM 64
#define BT (BB*TT)        // 4096
#define N3 (3*DD)         // 3072
#define NROWS (BB*HH*TT)  // 65536 attention rows
#define K1ATT 0.18033688011112042f   // (1/8) * log2(e), folded into Q

#define SPLIT 2
#define KVLEN (TT/SPLIT)   // 1024 keys per split
#define NTILE (KVLEN/32)   // 32 tiles per split

// ============================================================
// Fused prep kernel (block-range dispatch)
// ============================================================
DEV_INLINE void do_transpose(const float* __restrict__ in, unsigned short* __restrict__ out,
                             int K, int N, int bx, float (*tile)[66], int tid) {
    int nb = N >> 6;
    int n0 = (bx % nb) * 64, k0 = (bx / nb) * 64;
    int tx = tid & 63, ty = tid >> 6;
#pragma unroll
    for (int r = ty; r < 64; r += 4)
        tile[r][tx] = in[(size_t)(k0 + r) * N + n0 + tx];
    __syncthreads();
#pragma unroll
    for (int r = ty; r < 64; r += 4)
        out[(size_t)(n0 + r) * K + k0 + tx] = f2bf(tile[tx][r]);
}

__global__ __launch_bounds__(256)
void k_prep(const float* __restrict__ x, const float* __restrict__ W_qkv,
            const float* __restrict__ W_out, const unsigned char* __restrict__ mask,
            unsigned short* __restrict__ xb, float2* __restrict__ cs,
            unsigned short* __restrict__ wqkvt, unsigned short* __restrict__ woutt,
            unsigned* __restrict__ mbits) {
    __shared__ float tile[64][66];
    const int bid = blockIdx.x, tid = threadIdx.x;
    if (bid < 4096) {
        int i = bid * 256 + tid;
        f32x4 v = ((const f32x4*)x)[i];
        u16x4 o;
        o[0] = f2bf(v[0]); o[1] = f2bf(v[1]); o[2] = f2bf(v[2]); o[3] = f2bf(v[3]);
        ((u16x4*)xb)[i] = o;
    } else if (bid < 4352) {
        int i = (bid - 4096) * 256 + tid;
        int t = i >> 5, f = i & 31;
        float inv = powf(10000.0f, -(float)f / 32.0f);
        float ang = (float)t * inv;
        cs[i] = make_float2(cosf(ang), sinf(ang));
    } else if (bid < 5120) {
        do_transpose(W_qkv, wqkvt, DD, N3, bid - 4352, tile, tid);
    } else if (bid < 5376) {
        do_transpose(W_out, woutt, DD, DD, bid - 5120, tile, tid);
    } else {
        if (tid < BB * 64) {
            int b = tid >> 6, w = tid & 63;
            unsigned v = 0;
#pragma unroll
            for (int j = 0; j < 32; ++j)
                v |= (mask[b * TT + w * 32 + j] ? 1u : 0u) << j;
            mbits[tid] = v;
        }
    }
}

// ============================================================
// Shared BK=64 GEMM core: 128x128 tile, 16 K-steps of 64.
// LDS [128 rows][64 cols] bf16 (16 KB each for A,B), XOR-
// swizzled chunks (both-sides rule: linear gload_lds dest +
// inverse-swizzled global source chunk + swizzled ds_read).
// Halves the barrier count vs BK=32 (fixed per-step stall
// amortized over 2x the MFMA work).
// ============================================================
#define GEMM64_BODY(A_, Bt_, m0_, n0_, K_)                                          \
    f32x4 acc[4][4] = {};                                                           \
    {                                                                               \
        const int srow4 = (tid >> 3);          /* base row group for staging */     \
        (void)srow4;                                                                \
    }                                                                               \
    for (int k0 = 0; k0 < (K_); k0 += 64) {                                         \
        __syncthreads();                                                            \
        _Pragma("unroll")                                                           \
        for (int i = 0; i < 4; ++i) {                                               \
            int c    = i * 256 + tid;                                               \
            int row  = c >> 3;                                                      \
            int dstc = c & 7;                                                       \
            int srcc = dstc ^ (row & 7);                                            \
            unsigned short* ldsA = As + (size_t)(i * 256 + wave * 64) * 8;          \
            unsigned short* ldsB = Bs + (size_t)(i * 256 + wave * 64) * 8;          \
            gload16(A_  + (size_t)((m0_) + row) * (K_) + k0 + srcc * 8, ldsA);      \
            gload16(Bt_ + (size_t)((n0_) + row) * (K_) + k0 + srcc * 8, ldsB);      \
        }                                                                           \
        __syncthreads();                                                            \
        _Pragma("unroll")                                                           \
        for (int kk = 0; kk < 2; ++kk) {                                            \
            short8 af[4], bfr[4];                                                   \
            _Pragma("unroll")                                                       \
            for (int m = 0; m < 4; ++m) {                                           \
                int R  = wr * 64 + m * 16 + lrow;                                   \
                int ch = (kk * 4 + (lane >> 4)) ^ (R & 7);                          \
                af[m] = *(const short8*)(As + R * 64 + ch * 8);                     \
            }                                                                       \
            _Pragma("unroll")                                                       \
            for (int n = 0; n < 4; ++n) {                                           \
                int R  = wc * 64 + n * 16 + lrow;                                   \
                int ch = (kk * 4 + (lane >> 4)) ^ (R & 7);                          \
                bfr[n] = *(const short8*)(Bs + R * 64 + ch * 8);                    \
            }                                                                       \
            _Pragma("unroll")                                                       \
            for (int m = 0; m < 4; ++m)                                             \
                _Pragma("unroll")                                                   \
                for (int n = 0; n < 4; ++n)                                         \
                    acc[m][n] = __builtin_amdgcn_mfma_f32_16x16x32_bf16(            \
                        af[m], bfr[n], acc[m][n], 0, 0, 0);                         \
        }                                                                           \
    }

// ============================================================
// QKV GEMM + fused bias + RoPE + scatter. BK=64 core.
// 1D grid, 2D XCD chunk: 8 XCDs as 4(m)x2(n).
// ============================================================
__global__ __launch_bounds__(256)
void k_gemm_qkv(const unsigned short* __restrict__ A,
                const unsigned short* __restrict__ Bt,
                const float* __restrict__ bias,
                const float2* __restrict__ cs,
                unsigned short* __restrict__ Qb,
                unsigned short* __restrict__ Kb,
                unsigned short* __restrict__ Vrow) {
    __shared__ unsigned short As[128 * 64];
    __shared__ unsigned short Bs[128 * 64];
    const int tid  = threadIdx.x;
    const int lane = tid & 63;
    const int wave = tid >> 6;
    const int wr = wave >> 1, wc = wave & 1;
    const int bid = blockIdx.x;
    const int xcd = bid & 7, loc = bid >> 3;                 // loc 0..95
    const int m0 = ((xcd >> 1) * 8 + (loc & 7)) * 128;       // 32 m-tiles
    const int n0 = ((xcd & 1) * 12 + (loc >> 3)) * 128;      // 24 n-tiles
    const int lrow = lane & 15;

    GEMM64_BODY(A, Bt, m0, n0, DD)

    const int part = n0 >> 10;                       // 0=Q 1=K 2=V
    const int n0c  = n0 + wc * 64;
    const int h    = ((n0 & 1023) + wc * 64) >> 6;

    if (part < 2) {
        unsigned short* Dst = part == 0 ? Qb : Kb;
        const float qs = part == 0 ? K1ATT : 1.0f;
#pragma unroll
        for (int m = 0; m < 4; ++m)
#pragma unroll
            for (int r = 0; r < 4; ++r) {
                int gm = m0 + wr * 64 + m * 16 + (lane >> 4) * 4 + r;
                int b = gm >> 11, t = gm & (TT - 1);
                size_t rowoff = ((size_t)(b * HH + h) * TT + t) * 64;
#pragma unroll
                for (int n = 0; n < 2; ++n) {
                    int dr = n * 16 + lrow;
                    float2 c2 = cs[t * 32 + dr];
                    float lo = acc[m][n][r]     + bias[n0c + dr];
                    float hi = acc[m][n + 2][r] + bias[n0c + 32 + dr];
                    Dst[rowoff + dr]      = f2bf((lo * c2.x - hi * c2.y) * qs);
                    Dst[rowoff + 32 + dr] = f2bf((hi * c2.x + lo * c2.y) * qs);
                }
            }
    } else {
#pragma unroll
        for (int m = 0; m < 4; ++m)
#pragma unroll
            for (int r = 0; r < 4; ++r) {
                int gm = m0 + wr * 64 + m * 16 + (lane >> 4) * 4 + r;
                int b = gm >> 11, t = gm & (TT - 1);
                size_t rowoff = ((size_t)(b * HH + h) * TT + t) * 64;
#pragma unroll
                for (int n = 0; n < 4; ++n) {
                    int d = n * 16 + lrow;
                    Vrow[rowoff + d] = f2bf(acc[m][n][r] + bias[n0c + d]);
                }
            }
    }
}

// ============================================================
// output GEMM: M=4096 N=1024 K=1024. BK=64 core.
// 1D grid 256 blocks; XCD chunk 8m x 4n.
// ============================================================
__global__ __launch_bounds__(256)
void k_gemm_bt(const unsigned short* __restrict__ A,
               const unsigned short* __restrict__ Bt,
               const float* __restrict__ bias,
               float* __restrict__ C) {
    __shared__ unsigned short As[128 * 64];
    __shared__ unsigned short Bs[128 * 64];
    const int tid  = threadIdx.x;
    const int lane = tid & 63;
    const int wave = tid >> 6;
    const int wr = wave >> 1, wc = wave & 1;
    const int bid = blockIdx.x;
    const int xcd = bid & 7, loc = bid >> 3;                 // loc 0..31
    const int m0 = ((xcd >> 1) * 8 + (loc & 7)) * 128;       // 32 m-tiles
    const int n0 = ((xcd & 1) * 4 + (loc >> 3)) * 128;       // 8 n-tiles
    const int lrow = lane & 15;
    const int N = DD;

    GEMM64_BODY(A, Bt, m0, n0, DD)

#pragma unroll
    for (int m = 0; m < 4; ++m) {
        int row = m0 + wr * 64 + m * 16 + (lane >> 4) * 4;
#pragma unroll
        for (int n = 0; n < 4; ++n) {
            int col = n0 + wc * 64 + n * 16 + lrow;
            float bv = bias[col];
#pragma unroll
            for (int r = 0; r < 4; ++r)
                C[(size_t)(row + r) * N + col] = acc[m][n][r] + bv;
        }
    }
}

// ============================================================
// V transpose (bf16): Vrow [B][H][T][64] -> Vt [B][H][64][T]
// ============================================================
__global__ void k_vtrans(const unsigned short* __restrict__ Vrow, unsigned short* __restrict__ Vt) {
    __shared__ unsigned short tile[64][66];
    int bh = blockIdx.y;
    int t0 = blockIdx.x * 64;
    int tx = threadIdx.x & 63, ty = threadIdx.x >> 6;
#pragma unroll
    for (int r = ty; r < 64; r += 4)
        tile[r][tx] = Vrow[((size_t)bh * TT + t0 + r) * 64 + tx];
    __syncthreads();
#pragma unroll
    for (int r = ty; r < 64; r += 4)
        Vt[((size_t)bh * 64 + r) * TT + t0 + tx] = tile[tx][r];
}

// ============================================================
// Flash attention (R13-proven, UNCHANGED): swapped-QK^T 32x32,
// KVBLK=32, LDS dbuf, fixed-max softmax, SPLIT=2, XCD swizzle.
// ============================================================
__global__ __launch_bounds__(256, 4)
void k_attn(const unsigned short* __restrict__ Q,
            const unsigned short* __restrict__ Kg,
            const unsigned short* __restrict__ Vt,
            const unsigned* __restrict__ mbits,
            float* __restrict__ Opart, float* __restrict__ lbuf) {
    __shared__ unsigned short lds[2][2][2048];   // [buf][K/V][32x64]
    const int tid = threadIdx.x, lane = tid & 63, wave = tid >> 6;
    const int bid = blockIdx.x;
    const int w   = (bid & 7) * 128 + (bid >> 3);
    const int qx  = w & 15;
    const int z   = (w >> 4) & 1;
    const int bh  = w >> 5;
    const int b   = bh >> 4;
    const int q0  = (qx * 4 + wave) * 32;
    const int lq  = lane & 31;
    const int hi  = lane >> 5;
    const int k0  = z * KVLEN;

    const unsigned short* Qp = Q  + ((size_t)bh * TT + q0) * 64;
    const unsigned short* Kp = Kg + (size_t)bh * TT * 64 + (size_t)k0 * 64;
    const unsigned short* Vp = Vt + (size_t)bh * 64 * TT + k0;

    unsigned mwv = mbits[b * 64 + z * 32 + lq];

    const int rr = wave * 8 + (lane >> 3);
    const int j  = (lane & 7) ^ (rr & 7);
    const size_t ksrc = (size_t)rr * 64 + j * 8;
    const int vd = rr + ((j >> 2) << 5);
    const size_t vsrc = (size_t)vd * TT + (j & 3) * 8;

    short8 qf[4];
#pragma unroll
    for (int c = 0; c < 4; ++c)
        qf[c] = *(const short8*)(Qp + lq * 64 + c * 16 + hi * 8);

    f32x16 o0 = {}, o1 = {};
    float lhalf = 0.f;
    const int rx = lq & 7;

    auto stage = [&](int tt, int buf) {
        gload16(Kp + (size_t)tt * 32 * 64 + ksrc, &lds[buf][0][wave * 512]);
        gload16(Vp + tt * 32 + vsrc,              &lds[buf][1][wave * 512]);
    };

    auto tile_compute = [&](const unsigned short* Kl, const unsigned short* Vl, int t) {
        short8 kf0 = *(const short8*)(Kl + lq * 64 + ((0 + hi) ^ rx) * 8);
        short8 kf1 = *(const short8*)(Kl + lq * 64 + ((2 + hi) ^ rx) * 8);
        short8 kf2 = *(const short8*)(Kl + lq * 64 + ((4 + hi) ^ rx) * 8);
        short8 kf3 = *(const short8*)(Kl + lq * 64 + ((6 + hi) ^ rx) * 8);
        short8 vf00 = *(const short8*)(Vl + lq * 64 + ((0 + hi) ^ rx) * 8);
        short8 vf10 = *(const short8*)(Vl + lq * 64 + ((2 + hi) ^ rx) * 8);
        short8 vf01 = *(const short8*)(Vl + lq * 64 + ((4 + hi) ^ rx) * 8);
        short8 vf11 = *(const short8*)(Vl + lq * 64 + ((6 + hi) ^ rx) * 8);

        f32x16 s = {};
        __builtin_amdgcn_s_setprio(1);
        s = __builtin_amdgcn_mfma_f32_32x32x16_bf16(kf0, qf[0], s, 0, 0, 0);
        s = __builtin_amdgcn_mfma_f32_32x32x16_bf16(kf1, qf[1], s, 0, 0, 0);
        s = __builtin_amdgcn_mfma_f32_32x32x16_bf16(kf2, qf[2], s, 0, 0, 0);
        s = __builtin_amdgcn_mfma_f32_32x32x16_bf16(kf3, qf[3], s, 0, 0, 0);
        __builtin_amdgcn_s_setprio(0);

        unsigned mw = __builtin_amdgcn_readlane(mwv, t);
        float p[16];
        if (mw) {
            unsigned bmh = mw >> (hi * 4);
#pragma unroll
            for (int r = 0; r < 16; ++r) {
                float v = s[r];
                if ((bmh >> ((r & 3) + 8 * (r >> 2))) & 1u) v = -INFINITY;
                p[r] = __builtin_amdgcn_exp2f(v);
            }
        } else {
#pragma unroll
            for (int r = 0; r < 16; ++r) p[r] = __builtin_amdgcn_exp2f(s[r]);
        }

        float ts[8];
#pragma unroll
        for (int r = 0; r < 8; ++r) ts[r] = p[r] + p[r + 8];
#pragma unroll
        for (int r = 0; r < 4; ++r) ts[r] = ts[r] + ts[r + 4];
        lhalf += (ts[0] + ts[1]) + (ts[2] + ts[3]);

        unsigned u[8];
#pragma unroll
        for (int i = 0; i < 8; ++i) u[i] = cvt_pk_bf16(p[2 * i], p[2 * i + 1]);

        unsigned s0 = hi ? u[0] : u[2];
        unsigned s1 = hi ? u[1] : u[3];
        unsigned s2 = hi ? u[4] : u[6];
        unsigned s3 = hi ? u[5] : u[7];
        unsigned r0 = __shfl_xor(s0, 32, 64);
        unsigned r1 = __shfl_xor(s1, 32, 64);
        unsigned r2 = __shfl_xor(s2, 32, 64);
        unsigned r3 = __shfl_xor(s3, 32, 64);

        union { unsigned w[4]; short8 v; } a0, a1;
        a0.w[0] = hi ? r0 : u[0];
        a0.w[1] = hi ? r1 : u[1];
        a0.w[2] = hi ? u[2] : r0;
        a0.w[3] = hi ? u[3] : r1;
        a1.w[0] = hi ? r2 : u[4];
        a1.w[1] = hi ? r3 : u[5];
        a1.w[2] = hi ? u[6] : r2;
        a1.w[3] = hi ? u[7] : r3;

        __builtin_amdgcn_s_setprio(1);
        o0 = __builtin_amdgcn_mfma_f32_32x32x16_bf16(a0.v, vf00, o0, 0, 0, 0);
        o0 = __builtin_amdgcn_mfma_f32_32x32x16_bf16(a1.v, vf10, o0, 0, 0, 0);
        o1 = __builtin_amdgcn_mfma_f32_32x32x16_bf16(a0.v, vf01, o1, 0, 0, 0);
        o1 = __builtin_amdgcn_mfma_f32_32x32x16_bf16(a1.v, vf11, o1, 0, 0, 0);
        __builtin_amdgcn_s_setprio(0);
    };

    stage(0, 0);
    __syncthreads();

    for (int t = 0; t < NTILE; t += 2) {
        stage(t + 1, 1);
        tile_compute(&lds[0][0][0], &lds[0][1][0], t);
        __syncthreads();
        if (t + 2 < NTILE) stage(t + 2, 0);
        tile_compute(&lds[1][0][0], &lds[1][1][0], t + 1);
        __syncthreads();
    }

    float ltot = lhalf + __shfl_xor(lhalf, 32, 64);
#pragma unroll
    for (int r = 0; r < 16; ++r) {
        int qrow = (r & 3) + 8 * (r >> 2) + 4 * hi;
        size_t row = (size_t)z * NROWS + (size_t)bh * TT + q0 + qrow;
        float* Orow = Opart + row * 64;
        Orow[lq]      = o0[r];
        Orow[32 + lq] = o1[r];
    }
    if (hi == 0)
        lbuf[(size_t)z * NROWS + (size_t)bh * TT + q0 + lq] = ltot;
}

// ============================================================
// combine 2 splits (fixed max): out = (O1+O2)/(l1+l2)
// ============================================================
__global__ void k_combine(const float* __restrict__ Opart, const float* __restrict__ lbuf,
                          unsigned short* __restrict__ Ob) {
    int i = blockIdx.x * 256 + threadIdx.x;
    int g  = i >> 4;
    int d4 = (i & 15) * 4;
    f32x4 va = *(const f32x4*)(Opart + (size_t)g * 64 + d4);
    f32x4 vb = *(const f32x4*)(Opart + ((size_t)NROWS + g) * 64 + d4);
    float inv = 1.0f / (lbuf[g] + lbuf[NROWS + g]);
    int bh = g >> 11, t = g & (TT - 1), bb = bh >> 4, h = bh & 15;
    unsigned short* orow = Ob + ((size_t)(bb * TT + t)) * DD + h * 64 + d4;
#pragma unroll
    for (int jj = 0; jj < 4; ++jj)
        orow[jj] = f2bf((va[jj] + vb[jj]) * inv);
}

// ============================================================
// launch — workspace aliasing: Opart region hosts xb/wqkvt/
// Vrow/cs (dead pre-attn); Ob aliases Qb (dead post-attn).
// ============================================================
extern "C" void kernel_launch(void* const* d_in, const int* in_sizes, int n_in,
                              void* d_out, int out_size, void* d_ws, size_t ws_size,
                              hipStream_t stream) {
    const float* x      = (const float*)d_in[0];
    const float* W_qkv  = (const float*)d_in[1];
    const float* b_qkv  = (const float*)d_in[2];
    const float* W_out  = (const float*)d_in[3];
    const float* b_out  = (const float*)d_in[4];
    const unsigned char* mask = (const unsigned char*)d_in[5];
    float* out = (float*)d_out;

    char* ws = (char*)d_ws;
    size_t off = 0;
    auto alloc = [&](size_t bytes) { char* p = ws + off; off += (bytes + 255) & ~(size_t)255; return p; };

    float* Opart = (float*)alloc((size_t)SPLIT * NROWS * 64 * 4);      // 33.6 MB
    unsigned short* xb    = (unsigned short*)((char*)Opart);
    unsigned short* wqkvt = (unsigned short*)((char*)Opart + (8u << 20));
    unsigned short* Vrow  = (unsigned short*)((char*)Opart + (14u << 20));
    float2*         cs    = (float2*)        ((char*)Opart + (23u << 20));

    unsigned short* woutt = (unsigned short*)alloc((size_t)DD * DD * 2);
    unsigned short* Qb    = (unsigned short*)alloc((size_t)BB * HH * TT * HDIM * 2);
    unsigned short* Kb    = (unsigned short*)alloc((size_t)BB * HH * TT * HDIM * 2);
    unsigned short* Vtb   = (unsigned short*)alloc((size_t)BB * HH * TT * HDIM * 2);
    float*          lbuf  = (float*)         alloc((size_t)SPLIT * NROWS * 4);
    unsigned*       mbits = (unsigned*)      alloc((size_t)BB * 64 * 4);
    unsigned short* Ob    = Qb;   // Qb dead after attn

    // 1. fused prep
    k_prep<<<5377, 256, 0, stream>>>(x, W_qkv, W_out, mask, xb, cs, wqkvt, woutt, mbits);
    // 2. QKV GEMM with fused bias+RoPE+scatter (BK=64)
    k_gemm_qkv<<<768, 256, 0, stream>>>(xb, wqkvt, b_qkv, cs, Qb, Kb, Vrow);
    // 3. V transpose (bf16)
    {
        dim3 g(TT / 64, BB * HH);
        k_vtrans<<<g, 256, 0, stream>>>(Vrow, Vtb);
    }
    // 4. attention: 1024 blocks, 2-way KV split
    k_attn<<<dim3(16 * BB * HH * SPLIT), 256, 0, stream>>>(Qb, Kb, Vtb, mbits, Opart, lbuf);
    {
        dim3 g((NROWS * 16) / 256);
        k_combine<<<g, 256, 0, stream>>>(Opart, lbuf, Ob);
    }
    // 5. output GEMM (BK=64)
    k_gemm_bt<<<256, 256, 0, stream>>>(Ob, woutt, b_out, out);
}

// Round 18
// 135.050 us; speedup vs baseline: 1.2205x; 1.0285x over previous
//
#include <hip/hip_runtime.h>
#include <hip/hip_bf16.h>
#include <math.h>

#define DEV_INLINE __device__ __forceinline__

typedef __attribute__((ext_vector_type(4))) float f32x4;
typedef __attribute__((ext_vector_type(16))) float f32x16;
typedef __attribute__((ext_vector_type(8))) short short8;
typedef __attribute__((ext_vector_type(4))) unsigned short u16x4;

// ---------- bf16 helpers ----------
DEV_INLINE unsigned short f2bf(float f) {
    unsigned int u = __builtin_bit_cast(unsigned int, f);
    u += 0x7FFFu + ((u >> 16) & 1u);   // round-to-nearest-even
    return (unsigned short)(u >> 16);
}
DEV_INLINE float bf2f(unsigned short h) {
    unsigned int u = ((unsigned int)h) << 16;
    return __builtin_bit_cast(float, u);
}
DEV_INLINE unsigned cvt_pk_bf16(float lo, float hi) {
    unsigned r;
    asm("v_cvt_pk_bf16_f32 %0, %1, %2" : "=v"(r) : "v"(lo), "v"(hi));
    return r;
}

// ---------- async global->LDS (16B per lane) ----------
DEV_INLINE void gload16(const void* g, void* l) {
    __builtin_amdgcn_global_load_lds(
        (const __attribute__((address_space(1))) unsigned int*)g,
        (__attribute__((address_space(3))) unsigned int*)l, 16, 0, 0);
}

// ---------- constants ----------
#define BB 2
#define TT 2048
#define DD 1024
#define HH 16
#define HDIM 64
#define BT (BB*TT)        // 4096
#define N3 (3*DD)         // 3072
#define NROWS (BB*HH*TT)  // 65536 attention rows
#define K1ATT 0.18033688011112042f   // (1/8) * log2(e), folded into Q

#define SPLIT 2
#define KVLEN (TT/SPLIT)   // 1024 keys per split
#define NTILE (KVLEN/32)   // 32 tiles per split

// ============================================================
// Fused prep kernel (block-range dispatch)
// ============================================================
DEV_INLINE void do_transpose(const float* __restrict__ in, unsigned short* __restrict__ out,
                             int K, int N, int bx, float (*tile)[66], int tid) {
    int nb = N >> 6;
    int n0 = (bx % nb) * 64, k0 = (bx / nb) * 64;
    int tx = tid & 63, ty = tid >> 6;
#pragma unroll
    for (int r = ty; r < 64; r += 4)
        tile[r][tx] = in[(size_t)(k0 + r) * N + n0 + tx];
    __syncthreads();
#pragma unroll
    for (int r = ty; r < 64; r += 4)
        out[(size_t)(n0 + r) * K + k0 + tx] = f2bf(tile[tx][r]);
}

__global__ __launch_bounds__(256)
void k_prep(const float* __restrict__ x, const float* __restrict__ W_qkv,
            const float* __restrict__ W_out, const unsigned char* __restrict__ mask,
            unsigned short* __restrict__ xb, float2* __restrict__ cs,
            unsigned short* __restrict__ wqkvt, unsigned short* __restrict__ woutt,
            unsigned* __restrict__ mbits) {
    __shared__ float tile[64][66];
    const int bid = blockIdx.x, tid = threadIdx.x;
    if (bid < 4096) {
        int i = bid * 256 + tid;
        f32x4 v = ((const f32x4*)x)[i];
        u16x4 o;
        o[0] = f2bf(v[0]); o[1] = f2bf(v[1]); o[2] = f2bf(v[2]); o[3] = f2bf(v[3]);
        ((u16x4*)xb)[i] = o;
    } else if (bid < 4352) {
        int i = (bid - 4096) * 256 + tid;
        int t = i >> 5, f = i & 31;
        float inv = powf(10000.0f, -(float)f / 32.0f);
        float ang = (float)t * inv;
        cs[i] = make_float2(cosf(ang), sinf(ang));
    } else if (bid < 5120) {
        do_transpose(W_qkv, wqkvt, DD, N3, bid - 4352, tile, tid);
    } else if (bid < 5376) {
        do_transpose(W_out, woutt, DD, DD, bid - 5120, tile, tid);
    } else {
        if (tid < BB * 64) {
            int b = tid >> 6, w = tid & 63;
            unsigned v = 0;
#pragma unroll
            for (int j = 0; j < 32; ++j)
                v |= (mask[b * TT + w * 32 + j] ? 1u : 0u) << j;
            mbits[tid] = v;
        }
    }
}

// ============================================================
// Shared BK=64 GEMM core (R17-proven): 128x128 tile, 16 K-steps.
// XOR-swizzled LDS (both-sides rule).
// ============================================================
#define GEMM64_BODY(A_, Bt_, m0_, n0_, K_)                                          \
    f32x4 acc[4][4] = {};                                                           \
    for (int k0 = 0; k0 < (K_); k0 += 64) {                                         \
        __syncthreads();                                                            \
        _Pragma("unroll")                                                           \
        for (int i = 0; i < 4; ++i) {                                               \
            int c    = i * 256 + tid;                                               \
            int row  = c >> 3;                                                      \
            int dstc = c & 7;                                                       \
            int srcc = dstc ^ (row & 7);                                            \
            unsigned short* ldsA = As + (size_t)(i * 256 + wave * 64) * 8;          \
            unsigned short* ldsB = Bs + (size_t)(i * 256 + wave * 64) * 8;          \
            gload16(A_  + (size_t)((m0_) + row) * (K_) + k0 + srcc * 8, ldsA);      \
            gload16(Bt_ + (size_t)((n0_) + row) * (K_) + k0 + srcc * 8, ldsB);      \
        }                                                                           \
        __syncthreads();                                                            \
        _Pragma("unroll")                                                           \
        for (int kk = 0; kk < 2; ++kk) {                                            \
            short8 af[4], bfr[4];                                                   \
            _Pragma("unroll")                                                       \
            for (int m = 0; m < 4; ++m) {                                           \
                int R  = wr * 64 + m * 16 + lrow;                                   \
                int ch = (kk * 4 + (lane >> 4)) ^ (R & 7);                          \
                af[m] = *(const short8*)(As + R * 64 + ch * 8);                     \
            }                                                                       \
            _Pragma("unroll")                                                       \
            for (int n = 0; n < 4; ++n) {                                           \
                int R  = wc * 64 + n * 16 + lrow;                                   \
                int ch = (kk * 4 + (lane >> 4)) ^ (R & 7);                          \
                bfr[n] = *(const short8*)(Bs + R * 64 + ch * 8);                    \
            }                                                                       \
            _Pragma("unroll")                                                       \
            for (int m = 0; m < 4; ++m)                                             \
                _Pragma("unroll")                                                   \
                for (int n = 0; n < 4; ++n)                                         \
                    acc[m][n] = __builtin_amdgcn_mfma_f32_16x16x32_bf16(            \
                        af[m], bfr[n], acc[m][n], 0, 0, 0);                         \
        }                                                                           \
    }

// ============================================================
// QKV GEMM + fused bias + RoPE + scatter. BK=64 core.
// ============================================================
__global__ __launch_bounds__(256)
void k_gemm_qkv(const unsigned short* __restrict__ A,
                const unsigned short* __restrict__ Bt,
                const float* __restrict__ bias,
                const float2* __restrict__ cs,
                unsigned short* __restrict__ Qb,
                unsigned short* __restrict__ Kb,
                unsigned short* __restrict__ Vrow) {
    __shared__ unsigned short As[128 * 64];
    __shared__ unsigned short Bs[128 * 64];
    const int tid  = threadIdx.x;
    const int lane = tid & 63;
    const int wave = tid >> 6;
    const int wr = wave >> 1, wc = wave & 1;
    const int bid = blockIdx.x;
    const int xcd = bid & 7, loc = bid >> 3;                 // loc 0..95
    const int m0 = ((xcd >> 1) * 8 + (loc & 7)) * 128;       // 32 m-tiles
    const int n0 = ((xcd & 1) * 12 + (loc >> 3)) * 128;      // 24 n-tiles
    const int lrow = lane & 15;

    GEMM64_BODY(A, Bt, m0, n0, DD)

    const int part = n0 >> 10;                       // 0=Q 1=K 2=V
    const int n0c  = n0 + wc * 64;
    const int h    = ((n0 & 1023) + wc * 64) >> 6;

    if (part < 2) {
        unsigned short* Dst = part == 0 ? Qb : Kb;
        const float qs = part == 0 ? K1ATT : 1.0f;
#pragma unroll
        for (int m = 0; m < 4; ++m)
#pragma unroll
            for (int r = 0; r < 4; ++r) {
                int gm = m0 + wr * 64 + m * 16 + (lane >> 4) * 4 + r;
                int b = gm >> 11, t = gm & (TT - 1);
                size_t rowoff = ((size_t)(b * HH + h) * TT + t) * 64;
#pragma unroll
                for (int n = 0; n < 2; ++n) {
                    int dr = n * 16 + lrow;
                    float2 c2 = cs[t * 32 + dr];
                    float lo = acc[m][n][r]     + bias[n0c + dr];
                    float hi = acc[m][n + 2][r] + bias[n0c + 32 + dr];
                    Dst[rowoff + dr]      = f2bf((lo * c2.x - hi * c2.y) * qs);
                    Dst[rowoff + 32 + dr] = f2bf((hi * c2.x + lo * c2.y) * qs);
                }
            }
    } else {
#pragma unroll
        for (int m = 0; m < 4; ++m)
#pragma unroll
            for (int r = 0; r < 4; ++r) {
                int gm = m0 + wr * 64 + m * 16 + (lane >> 4) * 4 + r;
                int b = gm >> 11, t = gm & (TT - 1);
                size_t rowoff = ((size_t)(b * HH + h) * TT + t) * 64;
#pragma unroll
                for (int n = 0; n < 4; ++n) {
                    int d = n * 16 + lrow;
                    Vrow[rowoff + d] = f2bf(acc[m][n][r] + bias[n0c + d]);
                }
            }
    }
}

// ============================================================
// output GEMM: M=4096 N=1024 K=1024. BK=64 core.
// ============================================================
__global__ __launch_bounds__(256)
void k_gemm_bt(const unsigned short* __restrict__ A,
               const unsigned short* __restrict__ Bt,
               const float* __restrict__ bias,
               float* __restrict__ C) {
    __shared__ unsigned short As[128 * 64];
    __shared__ unsigned short Bs[128 * 64];
    const int tid  = threadIdx.x;
    const int lane = tid & 63;
    const int wave = tid >> 6;
    const int wr = wave >> 1, wc = wave & 1;
    const int bid = blockIdx.x;
    const int xcd = bid & 7, loc = bid >> 3;                 // loc 0..31
    const int m0 = ((xcd >> 1) * 8 + (loc & 7)) * 128;       // 32 m-tiles
    const int n0 = ((xcd & 1) * 4 + (loc >> 3)) * 128;       // 8 n-tiles
    const int lrow = lane & 15;
    const int N = DD;

    GEMM64_BODY(A, Bt, m0, n0, DD)

#pragma unroll
    for (int m = 0; m < 4; ++m) {
        int row = m0 + wr * 64 + m * 16 + (lane >> 4) * 4;
#pragma unroll
        for (int n = 0; n < 4; ++n) {
            int col = n0 + wc * 64 + n * 16 + lrow;
            float bv = bias[col];
#pragma unroll
            for (int r = 0; r < 4; ++r)
                C[(size_t)(row + r) * N + col] = acc[m][n][r] + bv;
        }
    }
}

// ============================================================
// V transpose (bf16): Vrow [B][H][T][64] -> Vt [B][H][64][T]
// ============================================================
__global__ void k_vtrans(const unsigned short* __restrict__ Vrow, unsigned short* __restrict__ Vt) {
    __shared__ unsigned short tile[64][66];
    int bh = blockIdx.y;
    int t0 = blockIdx.x * 64;
    int tx = threadIdx.x & 63, ty = threadIdx.x >> 6;
#pragma unroll
    for (int r = ty; r < 64; r += 4)
        tile[r][tx] = Vrow[((size_t)bh * TT + t0 + r) * 64 + tx];
    __syncthreads();
#pragma unroll
    for (int r = ty; r < 64; r += 4)
        Vt[((size_t)bh * 64 + r) * TT + t0 + tx] = tile[tx][r];
}

// ============================================================
// Flash attention (R13-proven structure): swapped-QK^T 32x32,
// KVBLK=32, LDS dbuf, fixed-max softmax, SPLIT=2, XCD swizzle.
// NEW: partials stored as bf16 (halves Opart traffic; one extra
// 2^-9 relative rounding before the combine -- within budget).
// ============================================================
__global__ __launch_bounds__(256, 4)
void k_attn(const unsigned short* __restrict__ Q,
            const unsigned short* __restrict__ Kg,
            const unsigned short* __restrict__ Vt,
            const unsigned* __restrict__ mbits,
            unsigned short* __restrict__ Opart, float* __restrict__ lbuf) {
    __shared__ unsigned short lds[2][2][2048];   // [buf][K/V][32x64]
    const int tid = threadIdx.x, lane = tid & 63, wave = tid >> 6;
    const int bid = blockIdx.x;
    const int w   = (bid & 7) * 128 + (bid >> 3);
    const int qx  = w & 15;
    const int z   = (w >> 4) & 1;
    const int bh  = w >> 5;
    const int b   = bh >> 4;
    const int q0  = (qx * 4 + wave) * 32;
    const int lq  = lane & 31;
    const int hi  = lane >> 5;
    const int k0  = z * KVLEN;

    const unsigned short* Qp = Q  + ((size_t)bh * TT + q0) * 64;
    const unsigned short* Kp = Kg + (size_t)bh * TT * 64 + (size_t)k0 * 64;
    const unsigned short* Vp = Vt + (size_t)bh * 64 * TT + k0;

    unsigned mwv = mbits[b * 64 + z * 32 + lq];

    const int rr = wave * 8 + (lane >> 3);
    const int j  = (lane & 7) ^ (rr & 7);
    const size_t ksrc = (size_t)rr * 64 + j * 8;
    const int vd = rr + ((j >> 2) << 5);
    const size_t vsrc = (size_t)vd * TT + (j & 3) * 8;

    short8 qf[4];
#pragma unroll
    for (int c = 0; c < 4; ++c)
        qf[c] = *(const short8*)(Qp + lq * 64 + c * 16 + hi * 8);

    f32x16 o0 = {}, o1 = {};
    float lhalf = 0.f;
    const int rx = lq & 7;

    auto stage = [&](int tt, int buf) {
        gload16(Kp + (size_t)tt * 32 * 64 + ksrc, &lds[buf][0][wave * 512]);
        gload16(Vp + tt * 32 + vsrc,              &lds[buf][1][wave * 512]);
    };

    auto tile_compute = [&](const unsigned short* Kl, const unsigned short* Vl, int t) {
        short8 kf0 = *(const short8*)(Kl + lq * 64 + ((0 + hi) ^ rx) * 8);
        short8 kf1 = *(const short8*)(Kl + lq * 64 + ((2 + hi) ^ rx) * 8);
        short8 kf2 = *(const short8*)(Kl + lq * 64 + ((4 + hi) ^ rx) * 8);
        short8 kf3 = *(const short8*)(Kl + lq * 64 + ((6 + hi) ^ rx) * 8);
        short8 vf00 = *(const short8*)(Vl + lq * 64 + ((0 + hi) ^ rx) * 8);
        short8 vf10 = *(const short8*)(Vl + lq * 64 + ((2 + hi) ^ rx) * 8);
        short8 vf01 = *(const short8*)(Vl + lq * 64 + ((4 + hi) ^ rx) * 8);
        short8 vf11 = *(const short8*)(Vl + lq * 64 + ((6 + hi) ^ rx) * 8);

        f32x16 s = {};
        __builtin_amdgcn_s_setprio(1);
        s = __builtin_amdgcn_mfma_f32_32x32x16_bf16(kf0, qf[0], s, 0, 0, 0);
        s = __builtin_amdgcn_mfma_f32_32x32x16_bf16(kf1, qf[1], s, 0, 0, 0);
        s = __builtin_amdgcn_mfma_f32_32x32x16_bf16(kf2, qf[2], s, 0, 0, 0);
        s = __builtin_amdgcn_mfma_f32_32x32x16_bf16(kf3, qf[3], s, 0, 0, 0);
        __builtin_amdgcn_s_setprio(0);

        unsigned mw = __builtin_amdgcn_readlane(mwv, t);
        float p[16];
        if (mw) {
            unsigned bmh = mw >> (hi * 4);
#pragma unroll
            for (int r = 0; r < 16; ++r) {
                float v = s[r];
                if ((bmh >> ((r & 3) + 8 * (r >> 2))) & 1u) v = -INFINITY;
                p[r] = __builtin_amdgcn_exp2f(v);
            }
        } else {
#pragma unroll
            for (int r = 0; r < 16; ++r) p[r] = __builtin_amdgcn_exp2f(s[r]);
        }

        float ts[8];
#pragma unroll
        for (int r = 0; r < 8; ++r) ts[r] = p[r] + p[r + 8];
#pragma unroll
        for (int r = 0; r < 4; ++r) ts[r] = ts[r] + ts[r + 4];
        lhalf += (ts[0] + ts[1]) + (ts[2] + ts[3]);

        unsigned u[8];
#pragma unroll
        for (int i = 0; i < 8; ++i) u[i] = cvt_pk_bf16(p[2 * i], p[2 * i + 1]);

        unsigned s0 = hi ? u[0] : u[2];
        unsigned s1 = hi ? u[1] : u[3];
        unsigned s2 = hi ? u[4] : u[6];
        unsigned s3 = hi ? u[5] : u[7];
        unsigned r0 = __shfl_xor(s0, 32, 64);
        unsigned r1 = __shfl_xor(s1, 32, 64);
        unsigned r2 = __shfl_xor(s2, 32, 64);
        unsigned r3 = __shfl_xor(s3, 32, 64);

        union { unsigned w[4]; short8 v; } a0, a1;
        a0.w[0] = hi ? r0 : u[0];
        a0.w[1] = hi ? r1 : u[1];
        a0.w[2] = hi ? u[2] : r0;
        a0.w[3] = hi ? u[3] : r1;
        a1.w[0] = hi ? r2 : u[4];
        a1.w[1] = hi ? r3 : u[5];
        a1.w[2] = hi ? u[6] : r2;
        a1.w[3] = hi ? u[7] : r3;

        __builtin_amdgcn_s_setprio(1);
        o0 = __builtin_amdgcn_mfma_f32_32x32x16_bf16(a0.v, vf00, o0, 0, 0, 0);
        o0 = __builtin_amdgcn_mfma_f32_32x32x16_bf16(a1.v, vf10, o0, 0, 0, 0);
        o1 = __builtin_amdgcn_mfma_f32_32x32x16_bf16(a0.v, vf01, o1, 0, 0, 0);
        o1 = __builtin_amdgcn_mfma_f32_32x32x16_bf16(a1.v, vf11, o1, 0, 0, 0);
        __builtin_amdgcn_s_setprio(0);
    };

    stage(0, 0);
    __syncthreads();

    for (int t = 0; t < NTILE; t += 2) {
        stage(t + 1, 1);
        tile_compute(&lds[0][0][0], &lds[0][1][0], t);
        __syncthreads();
        if (t + 2 < NTILE) stage(t + 2, 0);
        tile_compute(&lds[1][0][0], &lds[1][1][0], t + 1);
        __syncthreads();
    }

    // epilogue: unnormalized bf16 partials + f32 l
    float ltot = lhalf + __shfl_xor(lhalf, 32, 64);
#pragma unroll
    for (int r = 0; r < 16; ++r) {
        int qrow = (r & 3) + 8 * (r >> 2) + 4 * hi;
        size_t row = (size_t)z * NROWS + (size_t)bh * TT + q0 + qrow;
        unsigned short* Orow = Opart + row * 64;
        Orow[lq]      = f2bf(o0[r]);
        Orow[32 + lq] = f2bf(o1[r]);
    }
    if (hi == 0)
        lbuf[(size_t)z * NROWS + (size_t)bh * TT + q0 + lq] = ltot;
}

// ============================================================
// combine 2 splits (fixed max, bf16 partials):
// out = (O1+O2)/(l1+l2); vectorized short8 loads.
// ============================================================
__global__ void k_combine(const unsigned short* __restrict__ Opart,
                          const float* __restrict__ lbuf,
                          unsigned short* __restrict__ Ob) {
    int i = blockIdx.x * 256 + threadIdx.x;   // NROWS*8 threads, 8 cols each
    int g  = i >> 3;
    int d8 = (i & 7) * 8;
    short8 va = *(const short8*)(Opart + (size_t)g * 64 + d8);
    short8 vb = *(const short8*)(Opart + ((size_t)NROWS + g) * 64 + d8);
    float inv = 1.0f / (lbuf[g] + lbuf[NROWS + g]);
    int bh = g >> 11, t = g & (TT - 1), bb = bh >> 4, h = bh & 15;
    unsigned short* orow = Ob + ((size_t)(bb * TT + t)) * DD + h * 64 + d8;
    short8 o;
#pragma unroll
    for (int jj = 0; jj < 8; ++jj) {
        float v = (bf2f((unsigned short)va[jj]) + bf2f((unsigned short)vb[jj])) * inv;
        o[jj] = (short)f2bf(v);
    }
    *(short8*)orow = o;
}

// ============================================================
// launch
// ============================================================
extern "C" void kernel_launch(void* const* d_in, const int* in_sizes, int n_in,
                              void* d_out, int out_size, void* d_ws, size_t ws_size,
                              hipStream_t stream) {
    const float* x      = (const float*)d_in[0];
    const float* W_qkv  = (const float*)d_in[1];
    const float* b_qkv  = (const float*)d_in[2];
    const float* W_out  = (const float*)d_in[3];
    const float* b_out  = (const float*)d_in[4];
    const unsigned char* mask = (const unsigned char*)d_in[5];
    float* out = (float*)d_out;

    char* ws = (char*)d_ws;
    size_t off = 0;
    auto alloc = [&](size_t bytes) { char* p = ws + off; off += (bytes + 255) & ~(size_t)255; return p; };

    unsigned short* Opart = (unsigned short*)alloc((size_t)SPLIT * NROWS * 64 * 2);  // 16.8 MB
    unsigned short* xb    = (unsigned short*)alloc((size_t)BT * DD * 2);
    unsigned short* wqkvt = (unsigned short*)alloc((size_t)N3 * DD * 2);
    unsigned short* woutt = (unsigned short*)alloc((size_t)DD * DD * 2);
    unsigned short* Vrow  = (unsigned short*)alloc((size_t)BB * HH * TT * HDIM * 2);
    float2*         cs    = (float2*)        alloc((size_t)TT * 32 * 8);
    unsigned short* Qb    = (unsigned short*)alloc((size_t)BB * HH * TT * HDIM * 2);
    unsigned short* Kb    = (unsigned short*)alloc((size_t)BB * HH * TT * HDIM * 2);
    unsigned short* Vtb   = (unsigned short*)alloc((size_t)BB * HH * TT * HDIM * 2);
    float*          lbuf  = (float*)         alloc((size_t)SPLIT * NROWS * 4);
    unsigned*       mbits = (unsigned*)      alloc((size_t)BB * 64 * 4);
    unsigned short* Ob    = Qb;   // Qb dead after attn

    // 1. fused prep
    k_prep<<<5377, 256, 0, stream>>>(x, W_qkv, W_out, mask, xb, cs, wqkvt, woutt, mbits);
    // 2. QKV GEMM with fused bias+RoPE+scatter (BK=64)
    k_gemm_qkv<<<768, 256, 0, stream>>>(xb, wqkvt, b_qkv, cs, Qb, Kb, Vrow);
    // 3. V transpose (bf16)
    {
        dim3 g(TT / 64, BB * HH);
        k_vtrans<<<g, 256, 0, stream>>>(Vrow, Vtb);
    }
    // 4. attention: 1024 blocks, 2-way KV split
    k_attn<<<dim3(16 * BB * HH * SPLIT), 256, 0, stream>>>(Qb, Kb, Vtb, mbits, Opart, lbuf);
    {
        dim3 g((NROWS * 8) / 256);
        k_combine<<<g, 256, 0, stream>>>(Opart, lbuf, Ob);
    }
    // 5. output GEMM (BK=64)
    k_gemm_bt<<<256, 256, 0, stream>>>(Ob, woutt, b_out, out);
}

// Round 19
// 131.971 us; speedup vs baseline: 1.2490x; 1.0233x over previous
//
#include <hip/hip_runtime.h>
#include <hip/hip_bf16.h>
#include <math.h>

#define DEV_INLINE __device__ __forceinline__

typedef __attribute__((ext_vector_type(4))) float f32x4;
typedef __attribute__((ext_vector_type(16))) float f32x16;
typedef __attribute__((ext_vector_type(8))) short short8;
typedef __attribute__((ext_vector_type(4))) unsigned short u16x4;

// ---------- bf16 helpers ----------
DEV_INLINE unsigned short f2bf(float f) {
    unsigned int u = __builtin_bit_cast(unsigned int, f);
    u += 0x7FFFu + ((u >> 16) & 1u);   // round-to-nearest-even
    return (unsigned short)(u >> 16);
}
DEV_INLINE float bf2f(unsigned short h) {
    unsigned int u = ((unsigned int)h) << 16;
    return __builtin_bit_cast(float, u);
}
DEV_INLINE unsigned cvt_pk_bf16(float lo, float hi) {
    unsigned r;
    asm("v_cvt_pk_bf16_f32 %0, %1, %2" : "=v"(r) : "v"(lo), "v"(hi));
    return r;
}

// ---------- async global->LDS (16B per lane) ----------
DEV_INLINE void gload16(const void* g, void* l) {
    __builtin_amdgcn_global_load_lds(
        (const __attribute__((address_space(1))) unsigned int*)g,
        (__attribute__((address_space(3))) unsigned int*)l, 16, 0, 0);
}

// ---------- constants ----------
#define BB 2
#define TT 2048
#define DD 1024
#define HH 16
#define HDIM 64
#define BT (BB*TT)        // 4096
#define N3 (3*DD)         // 3072
#define NROWS (BB*HH*TT)  // 65536 attention rows
#define K1ATT 0.18033688011112042f   // (1/8) * log2(e), folded into Q

#define SPLIT 2
#define KVLEN (TT/SPLIT)   // 1024 keys per split
#define NTILE (KVLEN/32)   // 32 tiles per split

// ============================================================
// Fused prep kernel (block-range dispatch)
// ============================================================
DEV_INLINE void do_transpose(const float* __restrict__ in, unsigned short* __restrict__ out,
                             int K, int N, int bx, float (*tile)[66], int tid) {
    int nb = N >> 6;
    int n0 = (bx % nb) * 64, k0 = (bx / nb) * 64;
    int tx = tid & 63, ty = tid >> 6;
#pragma unroll
    for (int r = ty; r < 64; r += 4)
        tile[r][tx] = in[(size_t)(k0 + r) * N + n0 + tx];
    __syncthreads();
#pragma unroll
    for (int r = ty; r < 64; r += 4)
        out[(size_t)(n0 + r) * K + k0 + tx] = f2bf(tile[tx][r]);
}

__global__ __launch_bounds__(256)
void k_prep(const float* __restrict__ x, const float* __restrict__ W_qkv,
            const float* __restrict__ W_out, const unsigned char* __restrict__ mask,
            unsigned short* __restrict__ xb, float2* __restrict__ cs,
            unsigned short* __restrict__ wqkvt, unsigned short* __restrict__ woutt,
            unsigned* __restrict__ mbits) {
    __shared__ float tile[64][66];
    const int bid = blockIdx.x, tid = threadIdx.x;
    if (bid < 4096) {
        int i = bid * 256 + tid;
        f32x4 v = ((const f32x4*)x)[i];
        u16x4 o;
        o[0] = f2bf(v[0]); o[1] = f2bf(v[1]); o[2] = f2bf(v[2]); o[3] = f2bf(v[3]);
        ((u16x4*)xb)[i] = o;
    } else if (bid < 4352) {
        int i = (bid - 4096) * 256 + tid;
        int t = i >> 5, f = i & 31;
        float inv = powf(10000.0f, -(float)f / 32.0f);
        float ang = (float)t * inv;
        cs[i] = make_float2(cosf(ang), sinf(ang));
    } else if (bid < 5120) {
        do_transpose(W_qkv, wqkvt, DD, N3, bid - 4352, tile, tid);
    } else if (bid < 5376) {
        do_transpose(W_out, woutt, DD, DD, bid - 5120, tile, tid);
    } else {
        if (tid < BB * 64) {
            int b = tid >> 6, w = tid & 63;
            unsigned v = 0;
#pragma unroll
            for (int j = 0; j < 32; ++j)
                v |= (mask[b * TT + w * 32 + j] ? 1u : 0u) << j;
            mbits[tid] = v;
        }
    }
}

// ============================================================
// Shared BK=64 GEMM core (R17-proven): 128x128 tile, 16 K-steps.
// XOR-swizzled LDS (both-sides rule).
// ============================================================
#define GEMM64_BODY(A_, Bt_, m0_, n0_, K_)                                          \
    f32x4 acc[4][4] = {};                                                           \
    for (int k0 = 0; k0 < (K_); k0 += 64) {                                         \
        __syncthreads();                                                            \
        _Pragma("unroll")                                                           \
        for (int i = 0; i < 4; ++i) {                                               \
            int c    = i * 256 + tid;                                               \
            int row  = c >> 3;                                                      \
            int dstc = c & 7;                                                       \
            int srcc = dstc ^ (row & 7);                                            \
            unsigned short* ldsA = As + (size_t)(i * 256 + wave * 64) * 8;          \
            unsigned short* ldsB = Bs + (size_t)(i * 256 + wave * 64) * 8;          \
            gload16(A_  + (size_t)((m0_) + row) * (K_) + k0 + srcc * 8, ldsA);      \
            gload16(Bt_ + (size_t)((n0_) + row) * (K_) + k0 + srcc * 8, ldsB);      \
        }                                                                           \
        __syncthreads();                                                            \
        _Pragma("unroll")                                                           \
        for (int kk = 0; kk < 2; ++kk) {                                            \
            short8 af[4], bfr[4];                                                   \
            _Pragma("unroll")                                                       \
            for (int m = 0; m < 4; ++m) {                                           \
                int R  = wr * 64 + m * 16 + lrow;                                   \
                int ch = (kk * 4 + (lane >> 4)) ^ (R & 7);                          \
                af[m] = *(const short8*)(As + R * 64 + ch * 8);                     \
            }                                                                       \
            _Pragma("unroll")                                                       \
            for (int n = 0; n < 4; ++n) {                                           \
                int R  = wc * 64 + n * 16 + lrow;                                   \
                int ch = (kk * 4 + (lane >> 4)) ^ (R & 7);                          \
                bfr[n] = *(const short8*)(Bs + R * 64 + ch * 8);                    \
            }                                                                       \
            _Pragma("unroll")                                                       \
            for (int m = 0; m < 4; ++m)                                             \
                _Pragma("unroll")                                                   \
                for (int n = 0; n < 4; ++n)                                         \
                    acc[m][n] = __builtin_amdgcn_mfma_f32_16x16x32_bf16(            \
                        af[m], bfr[n], acc[m][n], 0, 0, 0);                         \
        }                                                                           \
    }

// ============================================================
// QKV GEMM + fused bias + RoPE + scatter. BK=64 core.
// V is written TRANSPOSED directly (Vt[b][h][d][t]): per (m,n)
// a lane's 4 acc values are 4 consecutive t at fixed d -> one
// u16x4 store; 4 quarter-groups x 4 m jointly cover the full
// 128-B Vt line (L2 merges, no HBM write amplification).
// Kills the Vrow buffer + k_vtrans kernel entirely.
// ============================================================
__global__ __launch_bounds__(256)
void k_gemm_qkv(const unsigned short* __restrict__ A,
                const unsigned short* __restrict__ Bt,
                const float* __restrict__ bias,
                const float2* __restrict__ cs,
                unsigned short* __restrict__ Qb,
                unsigned short* __restrict__ Kb,
                unsigned short* __restrict__ Vt) {
    __shared__ unsigned short As[128 * 64];
    __shared__ unsigned short Bs[128 * 64];
    const int tid  = threadIdx.x;
    const int lane = tid & 63;
    const int wave = tid >> 6;
    const int wr = wave >> 1, wc = wave & 1;
    const int bid = blockIdx.x;
    const int xcd = bid & 7, loc = bid >> 3;                 // loc 0..95
    const int m0 = ((xcd >> 1) * 8 + (loc & 7)) * 128;       // 32 m-tiles
    const int n0 = ((xcd & 1) * 12 + (loc >> 3)) * 128;      // 24 n-tiles
    const int lrow = lane & 15;

    GEMM64_BODY(A, Bt, m0, n0, DD)

    const int part = n0 >> 10;                       // 0=Q 1=K 2=V
    const int n0c  = n0 + wc * 64;
    const int h    = ((n0 & 1023) + wc * 64) >> 6;

    if (part < 2) {
        unsigned short* Dst = part == 0 ? Qb : Kb;
        const float qs = part == 0 ? K1ATT : 1.0f;
#pragma unroll
        for (int m = 0; m < 4; ++m)
#pragma unroll
            for (int r = 0; r < 4; ++r) {
                int gm = m0 + wr * 64 + m * 16 + (lane >> 4) * 4 + r;
                int b = gm >> 11, t = gm & (TT - 1);
                size_t rowoff = ((size_t)(b * HH + h) * TT + t) * 64;
#pragma unroll
                for (int n = 0; n < 2; ++n) {
                    int dr = n * 16 + lrow;
                    float2 c2 = cs[t * 32 + dr];
                    float lo = acc[m][n][r]     + bias[n0c + dr];
                    float hi = acc[m][n + 2][r] + bias[n0c + 32 + dr];
                    Dst[rowoff + dr]      = f2bf((lo * c2.x - hi * c2.y) * qs);
                    Dst[rowoff + 32 + dr] = f2bf((hi * c2.x + lo * c2.y) * qs);
                }
            }
    } else {
        // V: direct transposed write
#pragma unroll
        for (int m = 0; m < 4; ++m) {
            int gm0 = m0 + wr * 64 + m * 16 + (lane >> 4) * 4;  // 4 consecutive t
            int b = gm0 >> 11, t = gm0 & (TT - 1);
#pragma unroll
            for (int n = 0; n < 4; ++n) {
                int d = n * 16 + lrow;
                float bv = bias[n0c + d];
                u16x4 v;
#pragma unroll
                for (int r = 0; r < 4; ++r) v[r] = f2bf(acc[m][n][r] + bv);
                *(u16x4*)(Vt + ((size_t)(b * HH + h) * 64 + d) * TT + t) = v;
            }
        }
    }
}

// ============================================================
// output GEMM: M=4096 N=1024 K=1024. BK=64 core.
// ============================================================
__global__ __launch_bounds__(256)
void k_gemm_bt(const unsigned short* __restrict__ A,
               const unsigned short* __restrict__ Bt,
               const float* __restrict__ bias,
               float* __restrict__ C) {
    __shared__ unsigned short As[128 * 64];
    __shared__ unsigned short Bs[128 * 64];
    const int tid  = threadIdx.x;
    const int lane = tid & 63;
    const int wave = tid >> 6;
    const int wr = wave >> 1, wc = wave & 1;
    const int bid = blockIdx.x;
    const int xcd = bid & 7, loc = bid >> 3;                 // loc 0..31
    const int m0 = ((xcd >> 1) * 8 + (loc & 7)) * 128;       // 32 m-tiles
    const int n0 = ((xcd & 1) * 4 + (loc >> 3)) * 128;       // 8 n-tiles
    const int lrow = lane & 15;
    const int N = DD;

    GEMM64_BODY(A, Bt, m0, n0, DD)

#pragma unroll
    for (int m = 0; m < 4; ++m) {
        int row = m0 + wr * 64 + m * 16 + (lane >> 4) * 4;
#pragma unroll
        for (int n = 0; n < 4; ++n) {
            int col = n0 + wc * 64 + n * 16 + lrow;
            float bv = bias[col];
#pragma unroll
            for (int r = 0; r < 4; ++r)
                C[(size_t)(row + r) * N + col] = acc[m][n][r] + bv;
        }
    }
}

// ============================================================
// Flash attention (R13-proven structure + bf16 partials):
// swapped-QK^T 32x32, KVBLK=32, LDS dbuf, fixed-max softmax,
// SPLIT=2, XCD swizzle.
// ============================================================
__global__ __launch_bounds__(256, 4)
void k_attn(const unsigned short* __restrict__ Q,
            const unsigned short* __restrict__ Kg,
            const unsigned short* __restrict__ Vt,
            const unsigned* __restrict__ mbits,
            unsigned short* __restrict__ Opart, float* __restrict__ lbuf) {
    __shared__ unsigned short lds[2][2][2048];   // [buf][K/V][32x64]
    const int tid = threadIdx.x, lane = tid & 63, wave = tid >> 6;
    const int bid = blockIdx.x;
    const int w   = (bid & 7) * 128 + (bid >> 3);
    const int qx  = w & 15;
    const int z   = (w >> 4) & 1;
    const int bh  = w >> 5;
    const int b   = bh >> 4;
    const int q0  = (qx * 4 + wave) * 32;
    const int lq  = lane & 31;
    const int hi  = lane >> 5;
    const int k0  = z * KVLEN;

    const unsigned short* Qp = Q  + ((size_t)bh * TT + q0) * 64;
    const unsigned short* Kp = Kg + (size_t)bh * TT * 64 + (size_t)k0 * 64;
    const unsigned short* Vp = Vt + (size_t)bh * 64 * TT + k0;

    unsigned mwv = mbits[b * 64 + z * 32 + lq];

    const int rr = wave * 8 + (lane >> 3);
    const int j  = (lane & 7) ^ (rr & 7);
    const size_t ksrc = (size_t)rr * 64 + j * 8;
    const int vd = rr + ((j >> 2) << 5);
    const size_t vsrc = (size_t)vd * TT + (j & 3) * 8;

    short8 qf[4];
#pragma unroll
    for (int c = 0; c < 4; ++c)
        qf[c] = *(const short8*)(Qp + lq * 64 + c * 16 + hi * 8);

    f32x16 o0 = {}, o1 = {};
    float lhalf = 0.f;
    const int rx = lq & 7;

    auto stage = [&](int tt, int buf) {
        gload16(Kp + (size_t)tt * 32 * 64 + ksrc, &lds[buf][0][wave * 512]);
        gload16(Vp + tt * 32 + vsrc,              &lds[buf][1][wave * 512]);
    };

    auto tile_compute = [&](const unsigned short* Kl, const unsigned short* Vl, int t) {
        short8 kf0 = *(const short8*)(Kl + lq * 64 + ((0 + hi) ^ rx) * 8);
        short8 kf1 = *(const short8*)(Kl + lq * 64 + ((2 + hi) ^ rx) * 8);
        short8 kf2 = *(const short8*)(Kl + lq * 64 + ((4 + hi) ^ rx) * 8);
        short8 kf3 = *(const short8*)(Kl + lq * 64 + ((6 + hi) ^ rx) * 8);
        short8 vf00 = *(const short8*)(Vl + lq * 64 + ((0 + hi) ^ rx) * 8);
        short8 vf10 = *(const short8*)(Vl + lq * 64 + ((2 + hi) ^ rx) * 8);
        short8 vf01 = *(const short8*)(Vl + lq * 64 + ((4 + hi) ^ rx) * 8);
        short8 vf11 = *(const short8*)(Vl + lq * 64 + ((6 + hi) ^ rx) * 8);

        f32x16 s = {};
        __builtin_amdgcn_s_setprio(1);
        s = __builtin_amdgcn_mfma_f32_32x32x16_bf16(kf0, qf[0], s, 0, 0, 0);
        s = __builtin_amdgcn_mfma_f32_32x32x16_bf16(kf1, qf[1], s, 0, 0, 0);
        s = __builtin_amdgcn_mfma_f32_32x32x16_bf16(kf2, qf[2], s, 0, 0, 0);
        s = __builtin_amdgcn_mfma_f32_32x32x16_bf16(kf3, qf[3], s, 0, 0, 0);
        __builtin_amdgcn_s_setprio(0);

        unsigned mw = __builtin_amdgcn_readlane(mwv, t);
        float p[16];
        if (mw) {
            unsigned bmh = mw >> (hi * 4);
#pragma unroll
            for (int r = 0; r < 16; ++r) {
                float v = s[r];
                if ((bmh >> ((r & 3) + 8 * (r >> 2))) & 1u) v = -INFINITY;
                p[r] = __builtin_amdgcn_exp2f(v);
            }
        } else {
#pragma unroll
            for (int r = 0; r < 16; ++r) p[r] = __builtin_amdgcn_exp2f(s[r]);
        }

        float ts[8];
#pragma unroll
        for (int r = 0; r < 8; ++r) ts[r] = p[r] + p[r + 8];
#pragma unroll
        for (int r = 0; r < 4; ++r) ts[r] = ts[r] + ts[r + 4];
        lhalf += (ts[0] + ts[1]) + (ts[2] + ts[3]);

        unsigned u[8];
#pragma unroll
        for (int i = 0; i < 8; ++i) u[i] = cvt_pk_bf16(p[2 * i], p[2 * i + 1]);

        unsigned s0 = hi ? u[0] : u[2];
        unsigned s1 = hi ? u[1] : u[3];
        unsigned s2 = hi ? u[4] : u[6];
        unsigned s3 = hi ? u[5] : u[7];
        unsigned r0 = __shfl_xor(s0, 32, 64);
        unsigned r1 = __shfl_xor(s1, 32, 64);
        unsigned r2 = __shfl_xor(s2, 32, 64);
        unsigned r3 = __shfl_xor(s3, 32, 64);

        union { unsigned w[4]; short8 v; } a0, a1;
        a0.w[0] = hi ? r0 : u[0];
        a0.w[1] = hi ? r1 : u[1];
        a0.w[2] = hi ? u[2] : r0;
        a0.w[3] = hi ? u[3] : r1;
        a1.w[0] = hi ? r2 : u[4];
        a1.w[1] = hi ? r3 : u[5];
        a1.w[2] = hi ? u[6] : r2;
        a1.w[3] = hi ? u[7] : r3;

        __builtin_amdgcn_s_setprio(1);
        o0 = __builtin_amdgcn_mfma_f32_32x32x16_bf16(a0.v, vf00, o0, 0, 0, 0);
        o0 = __builtin_amdgcn_mfma_f32_32x32x16_bf16(a1.v, vf10, o0, 0, 0, 0);
        o1 = __builtin_amdgcn_mfma_f32_32x32x16_bf16(a0.v, vf01, o1, 0, 0, 0);
        o1 = __builtin_amdgcn_mfma_f32_32x32x16_bf16(a1.v, vf11, o1, 0, 0, 0);
        __builtin_amdgcn_s_setprio(0);
    };

    stage(0, 0);
    __syncthreads();

    for (int t = 0; t < NTILE; t += 2) {
        stage(t + 1, 1);
        tile_compute(&lds[0][0][0], &lds[0][1][0], t);
        __syncthreads();
        if (t + 2 < NTILE) stage(t + 2, 0);
        tile_compute(&lds[1][0][0], &lds[1][1][0], t + 1);
        __syncthreads();
    }

    // epilogue: unnormalized bf16 partials + f32 l
    float ltot = lhalf + __shfl_xor(lhalf, 32, 64);
#pragma unroll
    for (int r = 0; r < 16; ++r) {
        int qrow = (r & 3) + 8 * (r >> 2) + 4 * hi;
        size_t row = (size_t)z * NROWS + (size_t)bh * TT + q0 + qrow;
        unsigned short* Orow = Opart + row * 64;
        Orow[lq]      = f2bf(o0[r]);
        Orow[32 + lq] = f2bf(o1[r]);
    }
    if (hi == 0)
        lbuf[(size_t)z * NROWS + (size_t)bh * TT + q0 + lq] = ltot;
}

// ============================================================
// combine 2 splits (fixed max, bf16 partials):
// out = (O1+O2)/(l1+l2); vectorized short8 loads.
// ============================================================
__global__ void k_combine(const unsigned short* __restrict__ Opart,
                          const float* __restrict__ lbuf,
                          unsigned short* __restrict__ Ob) {
    int i = blockIdx.x * 256 + threadIdx.x;   // NROWS*8 threads, 8 cols each
    int g  = i >> 3;
    int d8 = (i & 7) * 8;
    short8 va = *(const short8*)(Opart + (size_t)g * 64 + d8);
    short8 vb = *(const short8*)(Opart + ((size_t)NROWS + g) * 64 + d8);
    float inv = 1.0f / (lbuf[g] + lbuf[NROWS + g]);
    int bh = g >> 11, t = g & (TT - 1), bb = bh >> 4, h = bh & 15;
    unsigned short* orow = Ob + ((size_t)(bb * TT + t)) * DD + h * 64 + d8;
    short8 o;
#pragma unroll
    for (int jj = 0; jj < 8; ++jj) {
        float v = (bf2f((unsigned short)va[jj]) + bf2f((unsigned short)vb[jj])) * inv;
        o[jj] = (short)f2bf(v);
    }
    *(short8*)orow = o;
}

// ============================================================
// launch
// ============================================================
extern "C" void kernel_launch(void* const* d_in, const int* in_sizes, int n_in,
                              void* d_out, int out_size, void* d_ws, size_t ws_size,
                              hipStream_t stream) {
    const float* x      = (const float*)d_in[0];
    const float* W_qkv  = (const float*)d_in[1];
    const float* b_qkv  = (const float*)d_in[2];
    const float* W_out  = (const float*)d_in[3];
    const float* b_out  = (const float*)d_in[4];
    const unsigned char* mask = (const unsigned char*)d_in[5];
    float* out = (float*)d_out;

    char* ws = (char*)d_ws;
    size_t off = 0;
    auto alloc = [&](size_t bytes) { char* p = ws + off; off += (bytes + 255) & ~(size_t)255; return p; };

    unsigned short* Opart = (unsigned short*)alloc((size_t)SPLIT * NROWS * 64 * 2);  // 16.8 MB
    unsigned short* xb    = (unsigned short*)alloc((size_t)BT * DD * 2);
    unsigned short* wqkvt = (unsigned short*)alloc((size_t)N3 * DD * 2);
    unsigned short* woutt = (unsigned short*)alloc((size_t)DD * DD * 2);
    float2*         cs    = (float2*)        alloc((size_t)TT * 32 * 8);
    unsigned short* Qb    = (unsigned short*)alloc((size_t)BB * HH * TT * HDIM * 2);
    unsigned short* Kb    = (unsigned short*)alloc((size_t)BB * HH * TT * HDIM * 2);
    unsigned short* Vtb   = (unsigned short*)alloc((size_t)BB * HH * TT * HDIM * 2);
    float*          lbuf  = (float*)         alloc((size_t)SPLIT * NROWS * 4);
    unsigned*       mbits = (unsigned*)      alloc((size_t)BB * 64 * 4);
    unsigned short* Ob    = Qb;   // Qb dead after attn

    // 1. fused prep
    k_prep<<<5377, 256, 0, stream>>>(x, W_qkv, W_out, mask, xb, cs, wqkvt, woutt, mbits);
    // 2. QKV GEMM with fused bias+RoPE+scatter, V written transposed (BK=64)
    k_gemm_qkv<<<768, 256, 0, stream>>>(xb, wqkvt, b_qkv, cs, Qb, Kb, Vtb);
    // 3. attention: 1024 blocks, 2-way KV split
    k_attn<<<dim3(16 * BB * HH * SPLIT), 256, 0, stream>>>(Qb, Kb, Vtb, mbits, Opart, lbuf);
    {
        dim3 g((NROWS * 8) / 256);
        k_combine<<<g, 256, 0, stream>>>(Opart, lbuf, Ob);
    }
    // 4. output GEMM (BK=64)
    k_gemm_bt<<<256, 256, 0, stream>>>(Ob, woutt, b_out, out);
}

// Round 20
// 130.209 us; speedup vs baseline: 1.2659x; 1.0135x over previous
//
#include <hip/hip_runtime.h>
#include <hip/hip_bf16.h>
#include <math.h>

#define DEV_INLINE __device__ __forceinline__

typedef __attribute__((ext_vector_type(4))) float f32x4;
typedef __attribute__((ext_vector_type(16))) float f32x16;
typedef __attribute__((ext_vector_type(8))) short short8;
typedef __attribute__((ext_vector_type(4))) unsigned short u16x4;

// ---------- bf16 helpers ----------
DEV_INLINE unsigned short f2bf(float f) {
    unsigned int u = __builtin_bit_cast(unsigned int, f);
    u += 0x7FFFu + ((u >> 16) & 1u);   // round-to-nearest-even
    return (unsigned short)(u >> 16);
}
DEV_INLINE float bf2f(unsigned short h) {
    unsigned int u = ((unsigned int)h) << 16;
    return __builtin_bit_cast(float, u);
}
DEV_INLINE unsigned cvt_pk_bf16(float lo, float hi) {
    unsigned r;
    asm("v_cvt_pk_bf16_f32 %0, %1, %2" : "=v"(r) : "v"(lo), "v"(hi));
    return r;
}

// ---------- async global->LDS (16B per lane) ----------
DEV_INLINE void gload16(const void* g, void* l) {
    __builtin_amdgcn_global_load_lds(
        (const __attribute__((address_space(1))) unsigned int*)g,
        (__attribute__((address_space(3))) unsigned int*)l, 16, 0, 0);
}

// ---------- constants ----------
#define BB 2
#define TT 2048
#define DD 1024
#define HH 16
#define HDIM 64
#define BT (BB*TT)        // 4096
#define N3 (3*DD)         // 3072
#define NROWS (BB*HH*TT)  // 65536 attention rows
#define K1ATT 0.18033688011112042f   // (1/8) * log2(e), folded into Q

#define SPLIT 2
#define KVLEN (TT/SPLIT)   // 1024 keys per split
#define NTILE (KVLEN/32)   // 32 tiles per split

// ============================================================
// Fused prep kernel (block-range dispatch)
// ============================================================
DEV_INLINE void do_transpose(const float* __restrict__ in, unsigned short* __restrict__ out,
                             int K, int N, int bx, float (*tile)[66], int tid) {
    int nb = N >> 6;
    int n0 = (bx % nb) * 64, k0 = (bx / nb) * 64;
    int tx = tid & 63, ty = tid >> 6;
#pragma unroll
    for (int r = ty; r < 64; r += 4)
        tile[r][tx] = in[(size_t)(k0 + r) * N + n0 + tx];
    __syncthreads();
#pragma unroll
    for (int r = ty; r < 64; r += 4)
        out[(size_t)(n0 + r) * K + k0 + tx] = f2bf(tile[tx][r]);
}

__global__ __launch_bounds__(256)
void k_prep(const float* __restrict__ x, const float* __restrict__ W_qkv,
            const float* __restrict__ W_out, const unsigned char* __restrict__ mask,
            unsigned short* __restrict__ xb, float2* __restrict__ cs,
            unsigned short* __restrict__ wqkvt, unsigned short* __restrict__ woutt,
            unsigned* __restrict__ mbits) {
    __shared__ float tile[64][66];
    const int bid = blockIdx.x, tid = threadIdx.x;
    if (bid < 4096) {
        int i = bid * 256 + tid;
        f32x4 v = ((const f32x4*)x)[i];
        u16x4 o;
        o[0] = f2bf(v[0]); o[1] = f2bf(v[1]); o[2] = f2bf(v[2]); o[3] = f2bf(v[3]);
        ((u16x4*)xb)[i] = o;
    } else if (bid < 4352) {
        int i = (bid - 4096) * 256 + tid;
        int t = i >> 5, f = i & 31;
        float inv = powf(10000.0f, -(float)f / 32.0f);
        float ang = (float)t * inv;
        cs[i] = make_float2(cosf(ang), sinf(ang));
    } else if (bid < 5120) {
        do_transpose(W_qkv, wqkvt, DD, N3, bid - 4352, tile, tid);
    } else if (bid < 5376) {
        do_transpose(W_out, woutt, DD, DD, bid - 5120, tile, tid);
    } else {
        if (tid < BB * 64) {
            int b = tid >> 6, w = tid & 63;
            unsigned v = 0;
#pragma unroll
            for (int j = 0; j < 32; ++j)
                v |= (mask[b * TT + w * 32 + j] ? 1u : 0u) << j;
            mbits[tid] = v;
        }
    }
}

// ============================================================
// Shared BK=64 GEMM core (R17-proven): 128x128 tile, 16 K-steps.
// XOR-swizzled LDS (both-sides rule).
// ============================================================
#define GEMM64_BODY(A_, Bt_, m0_, n0_, K_)                                          \
    f32x4 acc[4][4] = {};                                                           \
    for (int k0 = 0; k0 < (K_); k0 += 64) {                                         \
        __syncthreads();                                                            \
        _Pragma("unroll")                                                           \
        for (int i = 0; i < 4; ++i) {                                               \
            int c    = i * 256 + tid;                                               \
            int row  = c >> 3;                                                      \
            int dstc = c & 7;                                                       \
            int srcc = dstc ^ (row & 7);                                            \
            unsigned short* ldsA = As + (size_t)(i * 256 + wave * 64) * 8;          \
            unsigned short* ldsB = Bs + (size_t)(i * 256 + wave * 64) * 8;          \
            gload16(A_  + (size_t)((m0_) + row) * (K_) + k0 + srcc * 8, ldsA);      \
            gload16(Bt_ + (size_t)((n0_) + row) * (K_) + k0 + srcc * 8, ldsB);      \
        }                                                                           \
        __syncthreads();                                                            \
        _Pragma("unroll")                                                           \
        for (int kk = 0; kk < 2; ++kk) {                                            \
            short8 af[4], bfr[4];                                                   \
            _Pragma("unroll")                                                       \
            for (int m = 0; m < 4; ++m) {                                           \
                int R  = wr * 64 + m * 16 + lrow;                                   \
                int ch = (kk * 4 + (lane >> 4)) ^ (R & 7);                          \
                af[m] = *(const short8*)(As + R * 64 + ch * 8);                     \
            }                                                                       \
            _Pragma("unroll")                                                       \
            for (int n = 0; n < 4; ++n) {                                           \
                int R  = wc * 64 + n * 16 + lrow;                                   \
                int ch = (kk * 4 + (lane >> 4)) ^ (R & 7);                          \
                bfr[n] = *(const short8*)(Bs + R * 64 + ch * 8);                    \
            }                                                                       \
            _Pragma("unroll")                                                       \
            for (int m = 0; m < 4; ++m)                                             \
                _Pragma("unroll")                                                   \
                for (int n = 0; n < 4; ++n)                                         \
                    acc[m][n] = __builtin_amdgcn_mfma_f32_16x16x32_bf16(            \
                        af[m], bfr[n], acc[m][n], 0, 0, 0);                         \
        }                                                                           \
    }

// ============================================================
// QKV GEMM + fused bias + RoPE + scatter. BK=64 core.
// V written transposed directly (R19-proven).
// ============================================================
__global__ __launch_bounds__(256)
void k_gemm_qkv(const unsigned short* __restrict__ A,
                const unsigned short* __restrict__ Bt,
                const float* __restrict__ bias,
                const float2* __restrict__ cs,
                unsigned short* __restrict__ Qb,
                unsigned short* __restrict__ Kb,
                unsigned short* __restrict__ Vt) {
    __shared__ unsigned short As[128 * 64];
    __shared__ unsigned short Bs[128 * 64];
    const int tid  = threadIdx.x;
    const int lane = tid & 63;
    const int wave = tid >> 6;
    const int wr = wave >> 1, wc = wave & 1;
    const int bid = blockIdx.x;
    const int xcd = bid & 7, loc = bid >> 3;                 // loc 0..95
    const int m0 = ((xcd >> 1) * 8 + (loc & 7)) * 128;       // 32 m-tiles
    const int n0 = ((xcd & 1) * 12 + (loc >> 3)) * 128;      // 24 n-tiles
    const int lrow = lane & 15;

    GEMM64_BODY(A, Bt, m0, n0, DD)

    const int part = n0 >> 10;                       // 0=Q 1=K 2=V
    const int n0c  = n0 + wc * 64;
    const int h    = ((n0 & 1023) + wc * 64) >> 6;

    if (part < 2) {
        unsigned short* Dst = part == 0 ? Qb : Kb;
        const float qs = part == 0 ? K1ATT : 1.0f;
#pragma unroll
        for (int m = 0; m < 4; ++m)
#pragma unroll
            for (int r = 0; r < 4; ++r) {
                int gm = m0 + wr * 64 + m * 16 + (lane >> 4) * 4 + r;
                int b = gm >> 11, t = gm & (TT - 1);
                size_t rowoff = ((size_t)(b * HH + h) * TT + t) * 64;
#pragma unroll
                for (int n = 0; n < 2; ++n) {
                    int dr = n * 16 + lrow;
                    float2 c2 = cs[t * 32 + dr];
                    float lo = acc[m][n][r]     + bias[n0c + dr];
                    float hi = acc[m][n + 2][r] + bias[n0c + 32 + dr];
                    Dst[rowoff + dr]      = f2bf((lo * c2.x - hi * c2.y) * qs);
                    Dst[rowoff + 32 + dr] = f2bf((hi * c2.x + lo * c2.y) * qs);
                }
            }
    } else {
        // V: direct transposed write
#pragma unroll
        for (int m = 0; m < 4; ++m) {
            int gm0 = m0 + wr * 64 + m * 16 + (lane >> 4) * 4;  // 4 consecutive t
            int b = gm0 >> 11, t = gm0 & (TT - 1);
#pragma unroll
            for (int n = 0; n < 4; ++n) {
                int d = n * 16 + lrow;
                float bv = bias[n0c + d];
                u16x4 v;
#pragma unroll
                for (int r = 0; r < 4; ++r) v[r] = f2bf(acc[m][n][r] + bv);
                *(u16x4*)(Vt + ((size_t)(b * HH + h) * 64 + d) * TT + t) = v;
            }
        }
    }
}

// ============================================================
// Output GEMM with FUSED split-combine: C = attn_out @ Wout^T.
// A[m][k] = (Op0[g][d] + Op1[g][d]) / (l0[g]+l1[g]) computed on
// the fly during A-staging (reg-staged: 2x short8 + 2 scalars,
// combine, ds_write with write-side XOR swizzle). One K-step =
// one head (BK=64 == HDIM), so g=(b*16+h)*2048+t is chunk-
// uniform. Tile 64x128, grid 512 (2 blocks/CU); 4 waves as 1x4.
// ============================================================
__global__ __launch_bounds__(256)
void k_gemm_out(const unsigned short* __restrict__ Opart,
                const float* __restrict__ lbuf,
                const unsigned short* __restrict__ Bt,
                const float* __restrict__ bias,
                float* __restrict__ C) {
    __shared__ unsigned short As[64 * 64];     // 8 KB
    __shared__ unsigned short Bs[128 * 64];    // 16 KB
    const int tid  = threadIdx.x;
    const int lane = tid & 63;
    const int wave = tid >> 6;
    const int bid = blockIdx.x;
    // XCD chunk: 8 XCDs as 4(m)x2(n); per-XCD 16 m-tiles x 4 n-tiles
    const int xcd = bid & 7, loc = bid >> 3;                 // loc 0..63
    const int m0 = ((xcd >> 1) * 16 + (loc & 15)) * 64;      // 64 m-tiles
    const int n0 = ((xcd & 1) * 4 + (loc >> 4)) * 128;       // 8 n-tiles
    const int lrow = lane & 15;
    const int N = DD, K = DD;

    f32x4 acc[4][2] = {};

    for (int k0 = 0; k0 < K; k0 += 64) {
        const int h = k0 >> 6;                 // head for this K-step
        __syncthreads();
        // ---- A: reg-staged combine (2 slots/thread) ----
#pragma unroll
        for (int i = 0; i < 2; ++i) {
            int c     = i * 256 + tid;
            int row   = c >> 3;                // 0..63 (tile row)
            int chunk = c & 7;                 // d-chunk
            int gm = m0 + row;
            int b  = gm >> 11, t = gm & (TT - 1);
            size_t g = (size_t)(b * HH + h) * TT + t;
            short8 va = *(const short8*)(Opart + g * 64 + chunk * 8);
            short8 vb = *(const short8*)(Opart + ((size_t)NROWS + g) * 64 + chunk * 8);
            float inv = 1.0f / (lbuf[g] + lbuf[NROWS + g]);
            short8 o;
#pragma unroll
            for (int e = 0; e < 8; ++e)
                o[e] = (short)f2bf((bf2f((unsigned short)va[e]) + bf2f((unsigned short)vb[e])) * inv);
            *(short8*)(As + row * 64 + (chunk ^ (row & 7)) * 8) = o;
        }
        // ---- B: gload16 (4 slots/thread), inverse-swizzled source ----
#pragma unroll
        for (int i = 0; i < 4; ++i) {
            int c    = i * 256 + tid;
            int row  = c >> 3;
            int dstc = c & 7;
            int srcc = dstc ^ (row & 7);
            gload16(Bt + (size_t)(n0 + row) * K + k0 + srcc * 8,
                    &Bs[(size_t)(i * 256 + wave * 64) * 8]);
        }
        __syncthreads();
        // ---- compute: wave covers m 0..63, n wave*32..+32 ----
#pragma unroll
        for (int kk = 0; kk < 2; ++kk) {
            short8 af[4], bfr[2];
#pragma unroll
            for (int m = 0; m < 4; ++m) {
                int R  = m * 16 + lrow;
                int ch = (kk * 4 + (lane >> 4)) ^ (R & 7);
                af[m] = *(const short8*)(As + R * 64 + ch * 8);
            }
#pragma unroll
            for (int n = 0; n < 2; ++n) {
                int R  = wave * 32 + n * 16 + lrow;
                int ch = (kk * 4 + (lane >> 4)) ^ (R & 7);
                bfr[n] = *(const short8*)(Bs + R * 64 + ch * 8);
            }
#pragma unroll
            for (int m = 0; m < 4; ++m)
#pragma unroll
                for (int n = 0; n < 2; ++n)
                    acc[m][n] = __builtin_amdgcn_mfma_f32_16x16x32_bf16(
                        af[m], bfr[n], acc[m][n], 0, 0, 0);
        }
    }

#pragma unroll
    for (int m = 0; m < 4; ++m) {
        int row = m0 + m * 16 + (lane >> 4) * 4;
#pragma unroll
        for (int n = 0; n < 2; ++n) {
            int col = n0 + wave * 32 + n * 16 + lrow;
            float bv = bias[col];
#pragma unroll
            for (int r = 0; r < 4; ++r)
                C[(size_t)(row + r) * N + col] = acc[m][n][r] + bv;
        }
    }
}

// ============================================================
// Flash attention (R13-proven structure + bf16 partials):
// swapped-QK^T 32x32, KVBLK=32, LDS dbuf, fixed-max softmax,
// SPLIT=2, XCD swizzle.
// ============================================================
__global__ __launch_bounds__(256, 4)
void k_attn(const unsigned short* __restrict__ Q,
            const unsigned short* __restrict__ Kg,
            const unsigned short* __restrict__ Vt,
            const unsigned* __restrict__ mbits,
            unsigned short* __restrict__ Opart, float* __restrict__ lbuf) {
    __shared__ unsigned short lds[2][2][2048];   // [buf][K/V][32x64]
    const int tid = threadIdx.x, lane = tid & 63, wave = tid >> 6;
    const int bid = blockIdx.x;
    const int w   = (bid & 7) * 128 + (bid >> 3);
    const int qx  = w & 15;
    const int z   = (w >> 4) & 1;
    const int bh  = w >> 5;
    const int b   = bh >> 4;
    const int q0  = (qx * 4 + wave) * 32;
    const int lq  = lane & 31;
    const int hi  = lane >> 5;
    const int k0  = z * KVLEN;

    const unsigned short* Qp = Q  + ((size_t)bh * TT + q0) * 64;
    const unsigned short* Kp = Kg + (size_t)bh * TT * 64 + (size_t)k0 * 64;
    const unsigned short* Vp = Vt + (size_t)bh * 64 * TT + k0;

    unsigned mwv = mbits[b * 64 + z * 32 + lq];

    const int rr = wave * 8 + (lane >> 3);
    const int j  = (lane & 7) ^ (rr & 7);
    const size_t ksrc = (size_t)rr * 64 + j * 8;
    const int vd = rr + ((j >> 2) << 5);
    const size_t vsrc = (size_t)vd * TT + (j & 3) * 8;

    short8 qf[4];
#pragma unroll
    for (int c = 0; c < 4; ++c)
        qf[c] = *(const short8*)(Qp + lq * 64 + c * 16 + hi * 8);

    f32x16 o0 = {}, o1 = {};
    float lhalf = 0.f;
    const int rx = lq & 7;

    auto stage = [&](int tt, int buf) {
        gload16(Kp + (size_t)tt * 32 * 64 + ksrc, &lds[buf][0][wave * 512]);
        gload16(Vp + tt * 32 + vsrc,              &lds[buf][1][wave * 512]);
    };

    auto tile_compute = [&](const unsigned short* Kl, const unsigned short* Vl, int t) {
        short8 kf0 = *(const short8*)(Kl + lq * 64 + ((0 + hi) ^ rx) * 8);
        short8 kf1 = *(const short8*)(Kl + lq * 64 + ((2 + hi) ^ rx) * 8);
        short8 kf2 = *(const short8*)(Kl + lq * 64 + ((4 + hi) ^ rx) * 8);
        short8 kf3 = *(const short8*)(Kl + lq * 64 + ((6 + hi) ^ rx) * 8);
        short8 vf00 = *(const short8*)(Vl + lq * 64 + ((0 + hi) ^ rx) * 8);
        short8 vf10 = *(const short8*)(Vl + lq * 64 + ((2 + hi) ^ rx) * 8);
        short8 vf01 = *(const short8*)(Vl + lq * 64 + ((4 + hi) ^ rx) * 8);
        short8 vf11 = *(const short8*)(Vl + lq * 64 + ((6 + hi) ^ rx) * 8);

        f32x16 s = {};
        __builtin_amdgcn_s_setprio(1);
        s = __builtin_amdgcn_mfma_f32_32x32x16_bf16(kf0, qf[0], s, 0, 0, 0);
        s = __builtin_amdgcn_mfma_f32_32x32x16_bf16(kf1, qf[1], s, 0, 0, 0);
        s = __builtin_amdgcn_mfma_f32_32x32x16_bf16(kf2, qf[2], s, 0, 0, 0);
        s = __builtin_amdgcn_mfma_f32_32x32x16_bf16(kf3, qf[3], s, 0, 0, 0);
        __builtin_amdgcn_s_setprio(0);

        unsigned mw = __builtin_amdgcn_readlane(mwv, t);
        float p[16];
        if (mw) {
            unsigned bmh = mw >> (hi * 4);
#pragma unroll
            for (int r = 0; r < 16; ++r) {
                float v = s[r];
                if ((bmh >> ((r & 3) + 8 * (r >> 2))) & 1u) v = -INFINITY;
                p[r] = __builtin_amdgcn_exp2f(v);
            }
        } else {
#pragma unroll
            for (int r = 0; r < 16; ++r) p[r] = __builtin_amdgcn_exp2f(s[r]);
        }

        float ts[8];
#pragma unroll
        for (int r = 0; r < 8; ++r) ts[r] = p[r] + p[r + 8];
#pragma unroll
        for (int r = 0; r < 4; ++r) ts[r] = ts[r] + ts[r + 4];
        lhalf += (ts[0] + ts[1]) + (ts[2] + ts[3]);

        unsigned u[8];
#pragma unroll
        for (int i = 0; i < 8; ++i) u[i] = cvt_pk_bf16(p[2 * i], p[2 * i + 1]);

        unsigned s0 = hi ? u[0] : u[2];
        unsigned s1 = hi ? u[1] : u[3];
        unsigned s2 = hi ? u[4] : u[6];
        unsigned s3 = hi ? u[5] : u[7];
        unsigned r0 = __shfl_xor(s0, 32, 64);
        unsigned r1 = __shfl_xor(s1, 32, 64);
        unsigned r2 = __shfl_xor(s2, 32, 64);
        unsigned r3 = __shfl_xor(s3, 32, 64);

        union { unsigned w[4]; short8 v; } a0, a1;
        a0.w[0] = hi ? r0 : u[0];
        a0.w[1] = hi ? r1 : u[1];
        a0.w[2] = hi ? u[2] : r0;
        a0.w[3] = hi ? u[3] : r1;
        a1.w[0] = hi ? r2 : u[4];
        a1.w[1] = hi ? r3 : u[5];
        a1.w[2] = hi ? u[6] : r2;
        a1.w[3] = hi ? u[7] : r3;

        __builtin_amdgcn_s_setprio(1);
        o0 = __builtin_amdgcn_mfma_f32_32x32x16_bf16(a0.v, vf00, o0, 0, 0, 0);
        o0 = __builtin_amdgcn_mfma_f32_32x32x16_bf16(a1.v, vf10, o0, 0, 0, 0);
        o1 = __builtin_amdgcn_mfma_f32_32x32x16_bf16(a0.v, vf01, o1, 0, 0, 0);
        o1 = __builtin_amdgcn_mfma_f32_32x32x16_bf16(a1.v, vf11, o1, 0, 0, 0);
        __builtin_amdgcn_s_setprio(0);
    };

    stage(0, 0);
    __syncthreads();

    for (int t = 0; t < NTILE; t += 2) {
        stage(t + 1, 1);
        tile_compute(&lds[0][0][0], &lds[0][1][0], t);
        __syncthreads();
        if (t + 2 < NTILE) stage(t + 2, 0);
        tile_compute(&lds[1][0][0], &lds[1][1][0], t + 1);
        __syncthreads();
    }

    // epilogue: unnormalized bf16 partials + f32 l
    float ltot = lhalf + __shfl_xor(lhalf, 32, 64);
#pragma unroll
    for (int r = 0; r < 16; ++r) {
        int qrow = (r & 3) + 8 * (r >> 2) + 4 * hi;
        size_t row = (size_t)z * NROWS + (size_t)bh * TT + q0 + qrow;
        unsigned short* Orow = Opart + row * 64;
        Orow[lq]      = f2bf(o0[r]);
        Orow[32 + lq] = f2bf(o1[r]);
    }
    if (hi == 0)
        lbuf[(size_t)z * NROWS + (size_t)bh * TT + q0 + lq] = ltot;
}

// ============================================================
// launch
// ============================================================
extern "C" void kernel_launch(void* const* d_in, const int* in_sizes, int n_in,
                              void* d_out, int out_size, void* d_ws, size_t ws_size,
                              hipStream_t stream) {
    const float* x      = (const float*)d_in[0];
    const float* W_qkv  = (const float*)d_in[1];
    const float* b_qkv  = (const float*)d_in[2];
    const float* W_out  = (const float*)d_in[3];
    const float* b_out  = (const float*)d_in[4];
    const unsigned char* mask = (const unsigned char*)d_in[5];
    float* out = (float*)d_out;

    char* ws = (char*)d_ws;
    size_t off = 0;
    auto alloc = [&](size_t bytes) { char* p = ws + off; off += (bytes + 255) & ~(size_t)255; return p; };

    unsigned short* Opart = (unsigned short*)alloc((size_t)SPLIT * NROWS * 64 * 2);  // 16.8 MB
    unsigned short* xb    = (unsigned short*)alloc((size_t)BT * DD * 2);
    unsigned short* wqkvt = (unsigned short*)alloc((size_t)N3 * DD * 2);
    unsigned short* woutt = (unsigned short*)alloc((size_t)DD * DD * 2);
    float2*         cs    = (float2*)        alloc((size_t)TT * 32 * 8);
    unsigned short* Qb    = (unsigned short*)alloc((size_t)BB * HH * TT * HDIM * 2);
    unsigned short* Kb    = (unsigned short*)alloc((size_t)BB * HH * TT * HDIM * 2);
    unsigned short* Vtb   = (unsigned short*)alloc((size_t)BB * HH * TT * HDIM * 2);
    float*          lbuf  = (float*)         alloc((size_t)SPLIT * NROWS * 4);
    unsigned*       mbits = (unsigned*)      alloc((size_t)BB * 64 * 4);

    // 1. fused prep
    k_prep<<<5377, 256, 0, stream>>>(x, W_qkv, W_out, mask, xb, cs, wqkvt, woutt, mbits);
    // 2. QKV GEMM with fused bias+RoPE+scatter, V written transposed (BK=64)
    k_gemm_qkv<<<768, 256, 0, stream>>>(xb, wqkvt, b_qkv, cs, Qb, Kb, Vtb);
    // 3. attention: 1024 blocks, 2-way KV split
    k_attn<<<dim3(16 * BB * HH * SPLIT), 256, 0, stream>>>(Qb, Kb, Vtb, mbits, Opart, lbuf);
    // 4. output GEMM with fused split-combine (64x128 tiles, 512 blocks)
    k_gemm_out<<<512, 256, 0, stream>>>(Opart, lbuf, woutt, b_out, out);
}